// Round 21
// baseline (296.520 us; speedup 1.0000x reference)
//
#include <hip/hip_runtime.h>
#include <hip/hip_bf16.h>
#include <cfloat>
#include <climits>

#define DDIM 64
#define KSEL 16
#define WINDOW 4096          // T-estimation window
#define NCHUNK 64            // chunks of 64 queries (one per wave)
#define C1 0.017f            // > 2^-6: covers 2*bf16 dot error via Cauchy-Schwarz
#define C2 0.05f             // covers f32 accumulation + threshold rounding
#define RFAST 1024           // fast-path candidate limit (block recheck)
#define RBUF 1040            // LDS pack slots: fast path <=1024; fallback 16+1024
#define LSLOT 32             // per-(key,block) LDS hit slots (main filter)

typedef __attribute__((ext_vector_type(8))) short short8;
typedef __attribute__((ext_vector_type(4))) float f32x4;

// ---------------------------------------------------------------------------
// numpy pairwise-sum emulation for n=64 contiguous f32 (validated r3-r20).
// ---------------------------------------------------------------------------
__device__ __forceinline__ float np_sum64(const float* p) {
  float lane[16];
#pragma unroll
  for (int j = 0; j < 16; ++j)
    lane[j] = __fadd_rn(__fadd_rn(p[j], p[16 + j]),
                        __fadd_rn(p[32 + j], p[48 + j]));
  float u[8];
#pragma unroll
  for (int j = 0; j < 8; ++j) u[j] = __fadd_rn(lane[j], lane[j + 8]);
  float w[4];
#pragma unroll
  for (int j = 0; j < 4; ++j) w[j] = __fadd_rn(u[j], u[j + 4]);
  return __fadd_rn(__fadd_rn(w[0], w[2]), __fadd_rn(w[1], w[3]));
}

__device__ __forceinline__ void insert16(float* bd, int* bi, float cd, int ci) {
#pragma unroll
  for (int p = 0; p < KSEL; ++p) {
    bool sm = (cd < bd[p]) || (cd == bd[p] && ci < bi[p]);
    float td = bd[p]; int ti = bi[p];
    bd[p] = sm ? cd : td; bi[p] = sm ? ci : ti;
    cd = sm ? td : cd;   ci = sm ? ti : ci;
  }
}

// Monotone map: lexicographic (d,j) ascending == u64 ascending (j distinct).
__device__ __forceinline__ unsigned long long packdj(float d, int j) {
  unsigned db = __float_as_uint(d);
  db = (db & 0x80000000u) ? ~db : (db | 0x80000000u);
  return ((unsigned long long)db << 32) | (unsigned)j;
}

__device__ __forceinline__ unsigned mapmono(float d) {
  unsigned db = __float_as_uint(d);
  return (db & 0x80000000u) ? ~db : (db | 0x80000000u);
}

__device__ __forceinline__ float unmapmono(unsigned m) {
  return (m & 0x80000000u) ? __uint_as_float(m & 0x7fffffffu)
                           : __uint_as_float(~m);
}

// np-exact d2: sequential fmaf chain (BLAS per-element order), validated r3.
__device__ __forceinline__ float exact_d2(const float* __restrict__ k,
                                          const float* __restrict__ q,
                                          float k2, float q2) {
  float c = 0.f;
#pragma unroll
  for (int t = 0; t < DDIM; ++t) c = fmaf(k[t], q[t], c);
  return __fsub_rn(__fadd_rn(k2, q2), __fmul_rn(2.0f, c));
}

__device__ __forceinline__ unsigned bf2pack(float a, float b) {
  __hip_bfloat16 ha = __float2bfloat16(a), hb = __float2bfloat16(b);
  unsigned short ua = *reinterpret_cast<unsigned short*>(&ha);
  unsigned short ub = *reinterpret_cast<unsigned short*>(&hb);
  return (unsigned)ua | ((unsigned)ub << 16);
}

// Directed bf16 rounding (toward -inf / +inf); exact negation is ^0x8000.
__device__ __forceinline__ unsigned short bf_down(float x) {
  unsigned u = __float_as_uint(x);
  unsigned short hs = (unsigned short)(u >> 16);
  if ((u & 0xFFFFu) && x < 0.0f) hs += 1;
  return hs;
}
__device__ __forceinline__ unsigned short bf_up(float x) {
  unsigned u = __float_as_uint(x);
  unsigned short hs = (unsigned short)(u >> 16);
  if ((u & 0xFFFFu) && x > 0.0f) hs += 1;
  return hs;
}
__device__ __forceinline__ float bf_val(unsigned short h) {
  return __uint_as_float(((unsigned)h) << 16);
}

// f64 differentiable-path distance, same t=0..63 fma order as the original
// knn_dist_d (bit-identical).
__device__ __forceinline__ float fused_dist(const float4* __restrict__ klds,
                                            const float* __restrict__ qp) {
  const float4* q4 = reinterpret_cast<const float4*>(qp);
  double s = 0.0;
#pragma unroll
  for (int t = 0; t < 16; ++t) {
    float4 kk = klds[t], qv = q4[t];
    double d0 = (double)kk.x - (double)qv.x; s = fma(d0, d0, s);
    double d1 = (double)kk.y - (double)qv.y; s = fma(d1, d1, s);
    double d2 = (double)kk.z - (double)qv.z; s = fma(d2, d2, s);
    double d3 = (double)kk.w - (double)qv.w; s = fma(d3, d3, s);
  }
  return (float)s;
}

// ---------------------------------------------------------------------------
// Kernel A: np-exact row norms + bf16 conversion + sqrt norms + query-side
// threshold-ext fragment QE; also zeroes cnt (i < Nk). Validated r18-r20.
// ---------------------------------------------------------------------------
__global__ __launch_bounds__(256) void knn_norms_np(
    const float* __restrict__ keys, const float* __restrict__ queries,
    int Nk, int Nq, float* __restrict__ k2, float* __restrict__ q2,
    float* __restrict__ sk, float* __restrict__ sq,
    unsigned short* __restrict__ kbf, unsigned short* __restrict__ qbf,
    unsigned short* __restrict__ QE8, unsigned* __restrict__ cnt) {
  int i = blockIdx.x * 256 + threadIdx.x;
  if (i >= Nk + Nq) return;
  if (i < Nk) cnt[i] = 0u;
  bool isK = i < Nk;
  int r = isK ? i : i - Nk;
  const float4* row4 = reinterpret_cast<const float4*>(
      (isK ? keys : queries) + (size_t)r * DDIM);
  float p[DDIM]; unsigned hw[DDIM / 2];
#pragma unroll
  for (int t = 0; t < 16; ++t) {
    float4 v = row4[t];
    p[4 * t + 0] = __fmul_rn(v.x, v.x);
    p[4 * t + 1] = __fmul_rn(v.y, v.y);
    p[4 * t + 2] = __fmul_rn(v.z, v.z);
    p[4 * t + 3] = __fmul_rn(v.w, v.w);
    hw[2 * t + 0] = bf2pack(v.x, v.y);
    hw[2 * t + 1] = bf2pack(v.z, v.w);
  }
  float s = np_sum64(p);
  uint4* dst = reinterpret_cast<uint4*>((isK ? kbf : qbf) + (size_t)r * DDIM);
#pragma unroll
  for (int t = 0; t < 8; ++t)
    dst[t] = make_uint4(hw[4 * t], hw[4 * t + 1], hw[4 * t + 2], hw[4 * t + 3]);
  if (isK) { k2[r] = s; sk[r] = sqrtf(s); }
  else {
    q2[r] = s;
    float sv = sqrtf(s);
    sq[r] = sv;
    float h = 0.5f * s;
    unsigned short hhi = bf_down(h);            // h > 0: trunc, <= h
    float rem = h - bf_val(hhi);                // >= 0
    unsigned short hlo = (rem > 0.f) ? bf_down(rem) : (unsigned short)0;
    unsigned short e[8] = {0x3F80, bf_up(sv), hhi, hlo, 0, 0, 0, 0};
    uint4* qe = reinterpret_cast<uint4*>(QE8 + (size_t)r * 8);
    *qe = make_uint4((unsigned)e[0] | ((unsigned)e[1] << 16),
                     (unsigned)e[2] | ((unsigned)e[3] << 16), 0u, 0u);
  }
}

// ---------------------------------------------------------------------------
// Kernel C (chunkmin): MFMA upper-bound minima over the window, 64 chunks of
// 64 queries (one per wave). SINGLE WRITER per (key,chunk) slot — chunk =
// qt*4+w unique per block/wave, one l16==0 lane per key — so plain store
// (no atomicMin, no init; full coverage every call). Validated r20 math.
// ---------------------------------------------------------------------------
__global__ __launch_bounds__(256) void knn_chunkmin(
    const unsigned short* __restrict__ kbf, const unsigned short* __restrict__ qbf,
    const float* __restrict__ k2a, const float* __restrict__ ska,
    const float* __restrict__ q2a, const float* __restrict__ sqa,
    unsigned* __restrict__ cmin) {
  int tid = threadIdx.x, lane = tid & 63, w = tid >> 6;
  int kb = blockIdx.x & 127;
  int qt = blockIdx.x >> 7;              // 0..15
  int kbase = kb * 64;
  int qbase = qt * 256 + w * 64;
  int chunk = qbase >> 6;                // 0..63 (one per wave)
  int l16 = lane & 15, lg = lane >> 4;

  short8 a0[4], a1[4];
#pragma unroll
  for (int s = 0; s < 4; ++s) {
    const short8* krow = reinterpret_cast<const short8*>(
        kbf + (size_t)(kbase + s * 16 + l16) * DDIM);
    a0[s] = krow[lg]; a1[s] = krow[lg + 4];
  }
  float KA[16], KB[16];
#pragma unroll
  for (int s = 0; s < 4; ++s)
#pragma unroll
    for (int r = 0; r < 4; ++r) {
      int kk = kbase + s * 16 + lg * 4 + r;
      KA[s * 4 + r] = k2a[kk] + C2;
      KB[s * 4 + r] = C1 * ska[kk];
    }
  float mreg[16];
#pragma unroll
  for (int i = 0; i < 16; ++i) mreg[i] = FLT_MAX;

#pragma unroll
  for (int qs = 0; qs < 4; ++qs) {
    int q = qbase + qs * 16 + l16;
    const short8* qrow = reinterpret_cast<const short8*>(qbf + (size_t)q * DDIM);
    short8 b0 = qrow[lg], b1 = qrow[lg + 4];
    float q2l = q2a[q], sql = sqa[q];
    f32x4 acc[4];
#pragma unroll
    for (int s = 0; s < 4; ++s) {
      f32x4 z = {0.f, 0.f, 0.f, 0.f};
      z = __builtin_amdgcn_mfma_f32_16x16x32_bf16(a0[s], b0, z, 0, 0, 0);
      z = __builtin_amdgcn_mfma_f32_16x16x32_bf16(a1[s], b1, z, 0, 0, 0);
      acc[s] = z;
    }
#pragma unroll
    for (int s = 0; s < 4; ++s)
#pragma unroll
      for (int r = 0; r < 4; ++r) {
        int i = s * 4 + r;
        float u = fmaf(KB[i], sql, KA[i] + q2l) - 2.0f * acc[s][r];
        mreg[i] = fminf(mreg[i], u);
      }
  }
#pragma unroll
  for (int m = 1; m < 16; m <<= 1)
#pragma unroll
    for (int i = 0; i < 16; ++i)
      mreg[i] = fminf(mreg[i], __shfl_xor(mreg[i], m));
  if (l16 == 0) {
#pragma unroll
    for (int i = 0; i < 16; ++i) {
      int kk = kbase + (i >> 2) * 16 + lg * 4 + (i & 3);
      cmin[(size_t)kk * NCHUNK + chunk] = mapmono(mreg[i]);
    }
  }
}

// ---------------------------------------------------------------------------
// Kernel F (thresh3): thread per key. T = 16th-smallest of the 64 chunk
// minima (16 distinct pairs <= T => exact 16th <= T). Emits KE fragment
// (directed rounding -> filter superset). Validated r20.
// ---------------------------------------------------------------------------
__global__ __launch_bounds__(256) void knn_thresh3(
    const unsigned* __restrict__ cmin,
    const float* __restrict__ k2a, const float* __restrict__ ska,
    int Nk, unsigned short* __restrict__ KE8) {
  int key = blockIdx.x * 256 + threadIdx.x;
  if (key >= Nk) return;
  unsigned b[KSEL];
#pragma unroll
  for (int p = 0; p < KSEL; ++p) b[p] = 0xFFFFFFFFu;
  const unsigned* row = cmin + (size_t)key * NCHUNK;
  for (int c = 0; c < NCHUNK; ++c) {
    unsigned v = row[c];
    if (v < b[KSEL - 1]) {
      unsigned cv = v;
#pragma unroll
      for (int p = 0; p < KSEL; ++p) {
        bool sm = cv < b[p];
        unsigned t = b[p];
        b[p] = sm ? cv : t;
        cv = sm ? t : cv;
      }
    }
  }
  float T = unmapmono(b[KSEL - 1]);
  float psA = 0.5f * (k2a[key] - T - C2);
  float psB = -0.5f * C1 * ska[key];
  unsigned short e0 = (unsigned short)(bf_down(psA) ^ 0x8000);
  unsigned short e1 = (unsigned short)(bf_down(psB) ^ 0x8000);
  uint4* ke = reinterpret_cast<uint4*>(KE8 + (size_t)key * 8);
  *ke = make_uint4((unsigned)e0 | ((unsigned)e1 << 16),
                   0xBF80u | (0xBF80u << 16), 0u, 0u);
}

// ---------------------------------------------------------------------------
// Kernel G (MFMA filter v6, r18/r20-measured-best body): threshold folded
// into a third K=32 MFMA via KE/QE ext fragments; sign-test epilogue.
// Byte-identical to r20.
// ---------------------------------------------------------------------------
__global__ __launch_bounds__(256) void knn_filter(
    const unsigned short* __restrict__ kbf, const unsigned short* __restrict__ qbf,
    const unsigned short* __restrict__ KE8, const unsigned short* __restrict__ QE8,
    unsigned* __restrict__ cnt, unsigned short* __restrict__ cbuf, int CAP) {
  __shared__ int lcnt[64];
  __shared__ int lbase[64];
  __shared__ unsigned short lhit[64 * LSLOT];
  int tid = threadIdx.x;
  int lane = tid & 63, w = tid >> 6;
  int kb = blockIdx.x & 127;
  int qt = blockIdx.x >> 7;
  int kbase = kb * 64;
  int qwave = qt * 1024 + w * 256;
  int l16 = lane & 15, lg = lane >> 4;
  const short8 z8 = {0, 0, 0, 0, 0, 0, 0, 0};

  if (tid < 64) lcnt[tid] = 0;
  __syncthreads();

  short8 a0[4], a1[4], a2[4];
#pragma unroll
  for (int s = 0; s < 4; ++s) {
    const short8* krow = reinterpret_cast<const short8*>(
        kbf + (size_t)(kbase + s * 16 + l16) * DDIM);
    a0[s] = krow[lg]; a1[s] = krow[lg + 4];
    a2[s] = (lg == 0)
        ? *reinterpret_cast<const short8*>(KE8 + (size_t)(kbase + s * 16 + l16) * 8)
        : z8;
  }

  for (int qo = 0; qo < 4; ++qo) {
    int qbase = qwave + qo * 64;
#pragma unroll
    for (int qs = 0; qs < 4; ++qs) {
      int q = qbase + qs * 16 + l16;
      const short8* qrow = reinterpret_cast<const short8*>(qbf + (size_t)q * DDIM);
      short8 b0 = qrow[lg], b1 = qrow[lg + 4];
      short8 b2 = (lg == 0)
          ? *reinterpret_cast<const short8*>(QE8 + (size_t)q * 8)
          : z8;

      f32x4 acc[4];
#pragma unroll
      for (int s = 0; s < 4; ++s) {
        f32x4 z = {0.f, 0.f, 0.f, 0.f};
        z = __builtin_amdgcn_mfma_f32_16x16x32_bf16(a0[s], b0, z, 0, 0, 0);
        z = __builtin_amdgcn_mfma_f32_16x16x32_bf16(a1[s], b1, z, 0, 0, 0);
        z = __builtin_amdgcn_mfma_f32_16x16x32_bf16(a2[s], b2, z, 0, 0, 0);
        acc[s] = z;
      }
      unsigned m = 0;
#pragma unroll
      for (int s = 0; s < 4; ++s)
#pragma unroll
        for (int r = 0; r < 4; ++r)
          m |= (acc[s][r] > 0.0f) ? (1u << (s * 4 + r)) : 0u;
      while (m) {
        int b = __ffs(m) - 1; m &= m - 1;
        int kl = (b >> 2) * 16 + lg * 4 + (b & 3);
        int slot = atomicAdd(&lcnt[kl], 1);
        if (slot < LSLOT) lhit[kl * LSLOT + slot] = (unsigned short)q;
      }
    }
  }
  __syncthreads();
  if (tid < 64) {
    int lc = lcnt[tid];
    int key = kbase + tid;
    unsigned add = (lc > LSLOT) ? (unsigned)(CAP + 1000) : (unsigned)lc;
    lbase[tid] = (lc > 0) ? (int)atomicAdd(&cnt[key], add) : 0;
    lcnt[tid] = lc < LSLOT ? lc : LSLOT;
  }
  __syncthreads();
  for (int idx = tid; idx < 64 * LSLOT; idx += 256) {
    int kl = idx >> 5, sl = idx & (LSLOT - 1);
    if (sl < lcnt[kl]) {
      int pos = lbase[kl] + sl;
      if (pos < CAP)
        cbuf[(size_t)(kbase + kl) * CAP + pos] = lhit[kl * LSLOT + sl];
    }
  }
}

// ---------------------------------------------------------------------------
// Kernel H (recheck v7): r14-r20 body + FUSED f64 distance output (bit-
// identical t=0..63 fma order to the old knn_dist_d). Rank-count selection;
// chunked full-scan fallback.
// ---------------------------------------------------------------------------
__global__ __launch_bounds__(256) void knn_recheck(
    const float* __restrict__ keys, const float* __restrict__ queries,
    const float* __restrict__ k2a, const float* __restrict__ q2a,
    const unsigned* __restrict__ cnt, const unsigned short* __restrict__ cbuf,
    int CAP, int Nq, float* __restrict__ outIdx, float* __restrict__ outDist) {
  __shared__ unsigned long long packs[RBUF];       // 8.3 KB
  __shared__ unsigned long long cur16[KSEL];
  __shared__ float4 klds[16];
  int tid = threadIdx.x;
  int key = blockIdx.x;
  float myk2 = k2a[key];

  if (tid < 16)
    klds[tid] = reinterpret_cast<const float4*>(keys + (size_t)key * DDIM)[tid];
  __syncthreads();

  unsigned n = cnt[key];
  unsigned lim = (unsigned)((CAP < RFAST) ? CAP : RFAST);
  if (n <= lim) {
    const unsigned short* mc = cbuf + (size_t)key * CAP;
    int sub = tid & 3;
    int lanebase = (tid & 63) & ~3;
    for (unsigned base = 0; base < n; base += 64) {
      unsigned e = base + (unsigned)(tid >> 2);
      unsigned ec = (e < n) ? e : (n - 1);
      int j = mc[ec];
      const float4* Q = reinterpret_cast<const float4*>(queries + (size_t)j * DDIM);
      float4 rr[4];
      rr[0] = Q[sub];
      rr[1] = Q[sub + 4];
      rr[2] = Q[sub + 8];
      rr[3] = Q[sub + 12];
      float q2j = q2a[j];
      float c = 0.f;
#pragma unroll
      for (int seg = 0; seg < 16; ++seg) {
        float4 kk = klds[seg];
        float4 qq = rr[seg >> 2];
        float t = c;
        t = fmaf(kk.x, qq.x, t);
        t = fmaf(kk.y, qq.y, t);
        t = fmaf(kk.z, qq.z, t);
        t = fmaf(kk.w, qq.w, t);
        c = __shfl(t, lanebase + (seg & 3), 64);
      }
      if (e < n && sub == 0) {
        float d2 = __fsub_rn(__fadd_rn(myk2, q2j), __fmul_rn(2.0f, c));
        packs[e] = packdj(d2, j);
      }
    }
    __syncthreads();
    int N = (int)n;
    for (int i = tid; i < N; i += 256) {
      unsigned long long mp = packs[i];
      int c = 0;
      for (int m = 0; m < N; ++m) c += packs[m] < mp;
      if (c < KSEL) {
        int j = (int)(mp & 0xFFFFFFFFull);
        outIdx[(size_t)key * KSEL + c] = (float)j;
        outDist[(size_t)key * KSEL + c] =
            fused_dist(klds, queries + (size_t)j * DDIM);
      }
    }
    return;
  }

  // ---- fallback: exact full scan (correctness net, expected never) ----
  float bd[KSEL]; int bi[KSEL];
#pragma unroll
  for (int p = 0; p < KSEL; ++p) { bd[p] = FLT_MAX; bi[p] = INT_MAX; }
  const float* krow = keys + (size_t)key * DDIM;
  for (int j = tid; j < Nq; j += 256) {
    float d2 = exact_d2(krow, queries + (size_t)j * DDIM, myk2, q2a[j]);
    if (d2 < bd[KSEL - 1] || (d2 == bd[KSEL - 1] && j < bi[KSEL - 1]))
      insert16(bd, bi, d2, j);
  }
  if (tid < KSEL) cur16[tid] = ~0ull;
  __syncthreads();
  for (int r = 0; r < 4; ++r) {
    if ((tid >> 6) == r) {
#pragma unroll
      for (int p = 0; p < KSEL; ++p)
        packs[KSEL + (tid & 63) * KSEL + p] = packdj(bd[p], bi[p]);
    }
    if (tid < KSEL) packs[tid] = cur16[tid];
    __syncthreads();
    const int N = KSEL + 64 * KSEL;   // 1040
    for (int i = tid; i < N; i += 256) {
      unsigned long long mp = packs[i];
      int c = 0;
      for (int m = 0; m < N; ++m) c += packs[m] < mp;
      if (c < KSEL) cur16[c] = mp;
    }
    __syncthreads();
  }
  if (tid < KSEL) {
    int j = (int)(cur16[tid] & 0xFFFFFFFFull);
    outIdx[(size_t)key * KSEL + tid] = (float)j;
    outDist[(size_t)key * KSEL + tid] =
        fused_dist(klds, queries + (size_t)j * DDIM);
  }
}

// ---------------------------------------------------------------------------
extern "C" void kernel_launch(void* const* d_in, const int* in_sizes, int n_in,
                              void* d_out, int out_size, void* d_ws, size_t ws_size,
                              hipStream_t stream) {
  const float* keys    = (const float*)d_in[0];
  const float* queries = (const float*)d_in[1];
  int Nk = in_sizes[0] / DDIM;   // 8192
  int Nq = in_sizes[1] / DDIM;   // 32768
  float* out = (float*)d_out;

  char* wp = (char*)d_ws;
  float*    k2  = (float*)wp;  wp += (size_t)Nk * 4;
  float*    q2  = (float*)wp;  wp += (size_t)Nq * 4;
  float*    sk  = (float*)wp;  wp += (size_t)Nk * 4;
  float*    sq  = (float*)wp;  wp += (size_t)Nq * 4;
  unsigned* cnt = (unsigned*)wp; wp += (size_t)Nk * 4;
  unsigned* cmin = (unsigned*)wp; wp += (size_t)Nk * NCHUNK * 4;   // 2 MB
  unsigned short* kbf = (unsigned short*)wp; wp += (size_t)Nk * DDIM * 2;
  unsigned short* qbf = (unsigned short*)wp; wp += (size_t)Nq * DDIM * 2;
  unsigned short* KE8 = (unsigned short*)wp; wp += (size_t)Nk * 8 * 2;
  unsigned short* QE8 = (unsigned short*)wp; wp += (size_t)Nq * 8 * 2;
  size_t fixedBytes = (size_t)(wp - (char*)d_ws);
  unsigned short* cbuf = (unsigned short*)wp;
  long long rem = (long long)ws_size - (long long)fixedBytes;
  int CAP = (int)(rem / (2 * (long long)Nk));
  if (CAP > 2048) CAP = 2048;
  if (CAP < 16) CAP = 16;

  knn_norms_np<<<(Nk + Nq + 255) / 256, 256, 0, stream>>>(
      keys, queries, Nk, Nq, k2, q2, sk, sq, kbf, qbf, QE8, cnt);
  knn_chunkmin<<<128 * (WINDOW / 256), 256, 0, stream>>>(
      kbf, qbf, k2, sk, q2, sq, cmin);
  knn_thresh3<<<(Nk + 255) / 256, 256, 0, stream>>>(cmin, k2, sk, Nk, KE8);
  knn_filter<<<128 * (Nq / 1024), 256, 0, stream>>>(
      kbf, qbf, KE8, QE8, cnt, cbuf, CAP);
  knn_recheck<<<Nk, 256, 0, stream>>>(
      keys, queries, k2, q2, cnt, cbuf, CAP, Nq, out, out + (size_t)Nk * KSEL);
}

// Round 22
// 233.369 us; speedup vs baseline: 1.2706x; 1.2706x over previous
//
#include <hip/hip_runtime.h>
#include <hip/hip_bf16.h>
#include <cfloat>
#include <climits>

#define DDIM 64
#define KSEL 16
#define WINDOW 4096          // T-estimation window
#define NCHUNK 64            // chunks of 64 queries (one per wave)
#define C1 0.017f            // > 2^-6: covers 2*bf16 dot error via Cauchy-Schwarz
#define C2 0.05f             // covers f32 accumulation + threshold rounding
#define RFAST 1024           // fast-path candidate limit (block recheck)
#define RBUF 1040            // LDS pack slots: fast path <=1024; fallback 16+1024
#define LSLOT 32             // per-(key,block) LDS hit slots (main filter)

typedef __attribute__((ext_vector_type(8))) short short8;
typedef __attribute__((ext_vector_type(4))) float f32x4;

// ---------------------------------------------------------------------------
// numpy pairwise-sum emulation for n=64 contiguous f32 (validated r3-r21).
// ---------------------------------------------------------------------------
__device__ __forceinline__ float np_sum64(const float* p) {
  float lane[16];
#pragma unroll
  for (int j = 0; j < 16; ++j)
    lane[j] = __fadd_rn(__fadd_rn(p[j], p[16 + j]),
                        __fadd_rn(p[32 + j], p[48 + j]));
  float u[8];
#pragma unroll
  for (int j = 0; j < 8; ++j) u[j] = __fadd_rn(lane[j], lane[j + 8]);
  float w[4];
#pragma unroll
  for (int j = 0; j < 4; ++j) w[j] = __fadd_rn(u[j], u[j + 4]);
  return __fadd_rn(__fadd_rn(w[0], w[2]), __fadd_rn(w[1], w[3]));
}

__device__ __forceinline__ void insert16(float* bd, int* bi, float cd, int ci) {
#pragma unroll
  for (int p = 0; p < KSEL; ++p) {
    bool sm = (cd < bd[p]) || (cd == bd[p] && ci < bi[p]);
    float td = bd[p]; int ti = bi[p];
    bd[p] = sm ? cd : td; bi[p] = sm ? ci : ti;
    cd = sm ? td : cd;   ci = sm ? ti : ci;
  }
}

// Monotone map: lexicographic (d,j) ascending == u64 ascending (j distinct).
__device__ __forceinline__ unsigned long long packdj(float d, int j) {
  unsigned db = __float_as_uint(d);
  db = (db & 0x80000000u) ? ~db : (db | 0x80000000u);
  return ((unsigned long long)db << 32) | (unsigned)j;
}

__device__ __forceinline__ unsigned mapmono(float d) {
  unsigned db = __float_as_uint(d);
  return (db & 0x80000000u) ? ~db : (db | 0x80000000u);
}

__device__ __forceinline__ float unmapmono(unsigned m) {
  return (m & 0x80000000u) ? __uint_as_float(m & 0x7fffffffu)
                           : __uint_as_float(~m);
}

// np-exact d2: sequential fmaf chain (BLAS per-element order), validated r3.
__device__ __forceinline__ float exact_d2(const float* __restrict__ k,
                                          const float* __restrict__ q,
                                          float k2, float q2) {
  float c = 0.f;
#pragma unroll
  for (int t = 0; t < DDIM; ++t) c = fmaf(k[t], q[t], c);
  return __fsub_rn(__fadd_rn(k2, q2), __fmul_rn(2.0f, c));
}

__device__ __forceinline__ unsigned bf2pack(float a, float b) {
  __hip_bfloat16 ha = __float2bfloat16(a), hb = __float2bfloat16(b);
  unsigned short ua = *reinterpret_cast<unsigned short*>(&ha);
  unsigned short ub = *reinterpret_cast<unsigned short*>(&hb);
  return (unsigned)ua | ((unsigned)ub << 16);
}

// Directed bf16 rounding (toward -inf / +inf); exact negation is ^0x8000.
__device__ __forceinline__ unsigned short bf_down(float x) {
  unsigned u = __float_as_uint(x);
  unsigned short hs = (unsigned short)(u >> 16);
  if ((u & 0xFFFFu) && x < 0.0f) hs += 1;
  return hs;
}
__device__ __forceinline__ unsigned short bf_up(float x) {
  unsigned u = __float_as_uint(x);
  unsigned short hs = (unsigned short)(u >> 16);
  if ((u & 0xFFFFu) && x > 0.0f) hs += 1;
  return hs;
}
__device__ __forceinline__ float bf_val(unsigned short h) {
  return __uint_as_float(((unsigned)h) << 16);
}

// ---------------------------------------------------------------------------
// Kernel A: np-exact row norms + bf16 conversion + sqrt norms + query-side
// threshold-ext fragment QE; also zeroes cnt (i < Nk). Validated r18-r21.
// ---------------------------------------------------------------------------
__global__ __launch_bounds__(256) void knn_norms_np(
    const float* __restrict__ keys, const float* __restrict__ queries,
    int Nk, int Nq, float* __restrict__ k2, float* __restrict__ q2,
    float* __restrict__ sk, float* __restrict__ sq,
    unsigned short* __restrict__ kbf, unsigned short* __restrict__ qbf,
    unsigned short* __restrict__ QE8, unsigned* __restrict__ cnt) {
  int i = blockIdx.x * 256 + threadIdx.x;
  if (i >= Nk + Nq) return;
  if (i < Nk) cnt[i] = 0u;
  bool isK = i < Nk;
  int r = isK ? i : i - Nk;
  const float4* row4 = reinterpret_cast<const float4*>(
      (isK ? keys : queries) + (size_t)r * DDIM);
  float p[DDIM]; unsigned hw[DDIM / 2];
#pragma unroll
  for (int t = 0; t < 16; ++t) {
    float4 v = row4[t];
    p[4 * t + 0] = __fmul_rn(v.x, v.x);
    p[4 * t + 1] = __fmul_rn(v.y, v.y);
    p[4 * t + 2] = __fmul_rn(v.z, v.z);
    p[4 * t + 3] = __fmul_rn(v.w, v.w);
    hw[2 * t + 0] = bf2pack(v.x, v.y);
    hw[2 * t + 1] = bf2pack(v.z, v.w);
  }
  float s = np_sum64(p);
  uint4* dst = reinterpret_cast<uint4*>((isK ? kbf : qbf) + (size_t)r * DDIM);
#pragma unroll
  for (int t = 0; t < 8; ++t)
    dst[t] = make_uint4(hw[4 * t], hw[4 * t + 1], hw[4 * t + 2], hw[4 * t + 3]);
  if (isK) { k2[r] = s; sk[r] = sqrtf(s); }
  else {
    q2[r] = s;
    float sv = sqrtf(s);
    sq[r] = sv;
    float h = 0.5f * s;
    unsigned short hhi = bf_down(h);            // h > 0: trunc, <= h
    float rem = h - bf_val(hhi);                // >= 0
    unsigned short hlo = (rem > 0.f) ? bf_down(rem) : (unsigned short)0;
    unsigned short e[8] = {0x3F80, bf_up(sv), hhi, hlo, 0, 0, 0, 0};
    uint4* qe = reinterpret_cast<uint4*>(QE8 + (size_t)r * 8);
    *qe = make_uint4((unsigned)e[0] | ((unsigned)e[1] << 16),
                     (unsigned)e[2] | ((unsigned)e[3] << 16), 0u, 0u);
  }
}

// ---------------------------------------------------------------------------
// Kernel C (chunkmin): MFMA upper-bound minima over the window, 64 chunks of
// 64 queries (one per wave). Single writer per (key,chunk) slot -> plain
// store, no init. Validated r20/r21 math.
// ---------------------------------------------------------------------------
__global__ __launch_bounds__(256) void knn_chunkmin(
    const unsigned short* __restrict__ kbf, const unsigned short* __restrict__ qbf,
    const float* __restrict__ k2a, const float* __restrict__ ska,
    const float* __restrict__ q2a, const float* __restrict__ sqa,
    unsigned* __restrict__ cmin) {
  int tid = threadIdx.x, lane = tid & 63, w = tid >> 6;
  int kb = blockIdx.x & 127;
  int qt = blockIdx.x >> 7;              // 0..15
  int kbase = kb * 64;
  int qbase = qt * 256 + w * 64;
  int chunk = qbase >> 6;                // 0..63 (one per wave)
  int l16 = lane & 15, lg = lane >> 4;

  short8 a0[4], a1[4];
#pragma unroll
  for (int s = 0; s < 4; ++s) {
    const short8* krow = reinterpret_cast<const short8*>(
        kbf + (size_t)(kbase + s * 16 + l16) * DDIM);
    a0[s] = krow[lg]; a1[s] = krow[lg + 4];
  }
  float KA[16], KB[16];
#pragma unroll
  for (int s = 0; s < 4; ++s)
#pragma unroll
    for (int r = 0; r < 4; ++r) {
      int kk = kbase + s * 16 + lg * 4 + r;
      KA[s * 4 + r] = k2a[kk] + C2;
      KB[s * 4 + r] = C1 * ska[kk];
    }
  float mreg[16];
#pragma unroll
  for (int i = 0; i < 16; ++i) mreg[i] = FLT_MAX;

#pragma unroll
  for (int qs = 0; qs < 4; ++qs) {
    int q = qbase + qs * 16 + l16;
    const short8* qrow = reinterpret_cast<const short8*>(qbf + (size_t)q * DDIM);
    short8 b0 = qrow[lg], b1 = qrow[lg + 4];
    float q2l = q2a[q], sql = sqa[q];
    f32x4 acc[4];
#pragma unroll
    for (int s = 0; s < 4; ++s) {
      f32x4 z = {0.f, 0.f, 0.f, 0.f};
      z = __builtin_amdgcn_mfma_f32_16x16x32_bf16(a0[s], b0, z, 0, 0, 0);
      z = __builtin_amdgcn_mfma_f32_16x16x32_bf16(a1[s], b1, z, 0, 0, 0);
      acc[s] = z;
    }
#pragma unroll
    for (int s = 0; s < 4; ++s)
#pragma unroll
      for (int r = 0; r < 4; ++r) {
        int i = s * 4 + r;
        float u = fmaf(KB[i], sql, KA[i] + q2l) - 2.0f * acc[s][r];
        mreg[i] = fminf(mreg[i], u);
      }
  }
#pragma unroll
  for (int m = 1; m < 16; m <<= 1)
#pragma unroll
    for (int i = 0; i < 16; ++i)
      mreg[i] = fminf(mreg[i], __shfl_xor(mreg[i], m));
  if (l16 == 0) {
#pragma unroll
    for (int i = 0; i < 16; ++i) {
      int kk = kbase + (i >> 2) * 16 + lg * 4 + (i & 3);
      cmin[(size_t)kk * NCHUNK + chunk] = mapmono(mreg[i]);
    }
  }
}

// ---------------------------------------------------------------------------
// Kernel F (thresh3): thread per key. T = 16th-smallest of the 64 chunk
// minima (16 distinct pairs <= T => exact 16th <= T). Emits KE fragment
// (directed rounding -> filter superset). Validated r20/r21.
// ---------------------------------------------------------------------------
__global__ __launch_bounds__(256) void knn_thresh3(
    const unsigned* __restrict__ cmin,
    const float* __restrict__ k2a, const float* __restrict__ ska,
    int Nk, unsigned short* __restrict__ KE8) {
  int key = blockIdx.x * 256 + threadIdx.x;
  if (key >= Nk) return;
  unsigned b[KSEL];
#pragma unroll
  for (int p = 0; p < KSEL; ++p) b[p] = 0xFFFFFFFFu;
  const unsigned* row = cmin + (size_t)key * NCHUNK;
  for (int c = 0; c < NCHUNK; ++c) {
    unsigned v = row[c];
    if (v < b[KSEL - 1]) {
      unsigned cv = v;
#pragma unroll
      for (int p = 0; p < KSEL; ++p) {
        bool sm = cv < b[p];
        unsigned t = b[p];
        b[p] = sm ? cv : t;
        cv = sm ? t : cv;
      }
    }
  }
  float T = unmapmono(b[KSEL - 1]);
  float psA = 0.5f * (k2a[key] - T - C2);
  float psB = -0.5f * C1 * ska[key];
  unsigned short e0 = (unsigned short)(bf_down(psA) ^ 0x8000);
  unsigned short e1 = (unsigned short)(bf_down(psB) ^ 0x8000);
  uint4* ke = reinterpret_cast<uint4*>(KE8 + (size_t)key * 8);
  *ke = make_uint4((unsigned)e0 | ((unsigned)e1 << 16),
                   0xBF80u | (0xBF80u << 16), 0u, 0u);
}

// ---------------------------------------------------------------------------
// Kernel G (MFMA filter v6, r18/r20-measured-best body): threshold folded
// into a third K=32 MFMA via KE/QE ext fragments; sign-test epilogue.
// Byte-identical to r20.
// ---------------------------------------------------------------------------
__global__ __launch_bounds__(256) void knn_filter(
    const unsigned short* __restrict__ kbf, const unsigned short* __restrict__ qbf,
    const unsigned short* __restrict__ KE8, const unsigned short* __restrict__ QE8,
    unsigned* __restrict__ cnt, unsigned short* __restrict__ cbuf, int CAP) {
  __shared__ int lcnt[64];
  __shared__ int lbase[64];
  __shared__ unsigned short lhit[64 * LSLOT];
  int tid = threadIdx.x;
  int lane = tid & 63, w = tid >> 6;
  int kb = blockIdx.x & 127;
  int qt = blockIdx.x >> 7;
  int kbase = kb * 64;
  int qwave = qt * 1024 + w * 256;
  int l16 = lane & 15, lg = lane >> 4;
  const short8 z8 = {0, 0, 0, 0, 0, 0, 0, 0};

  if (tid < 64) lcnt[tid] = 0;
  __syncthreads();

  short8 a0[4], a1[4], a2[4];
#pragma unroll
  for (int s = 0; s < 4; ++s) {
    const short8* krow = reinterpret_cast<const short8*>(
        kbf + (size_t)(kbase + s * 16 + l16) * DDIM);
    a0[s] = krow[lg]; a1[s] = krow[lg + 4];
    a2[s] = (lg == 0)
        ? *reinterpret_cast<const short8*>(KE8 + (size_t)(kbase + s * 16 + l16) * 8)
        : z8;
  }

  for (int qo = 0; qo < 4; ++qo) {
    int qbase = qwave + qo * 64;
#pragma unroll
    for (int qs = 0; qs < 4; ++qs) {
      int q = qbase + qs * 16 + l16;
      const short8* qrow = reinterpret_cast<const short8*>(qbf + (size_t)q * DDIM);
      short8 b0 = qrow[lg], b1 = qrow[lg + 4];
      short8 b2 = (lg == 0)
          ? *reinterpret_cast<const short8*>(QE8 + (size_t)q * 8)
          : z8;

      f32x4 acc[4];
#pragma unroll
      for (int s = 0; s < 4; ++s) {
        f32x4 z = {0.f, 0.f, 0.f, 0.f};
        z = __builtin_amdgcn_mfma_f32_16x16x32_bf16(a0[s], b0, z, 0, 0, 0);
        z = __builtin_amdgcn_mfma_f32_16x16x32_bf16(a1[s], b1, z, 0, 0, 0);
        z = __builtin_amdgcn_mfma_f32_16x16x32_bf16(a2[s], b2, z, 0, 0, 0);
        acc[s] = z;
      }
      unsigned m = 0;
#pragma unroll
      for (int s = 0; s < 4; ++s)
#pragma unroll
        for (int r = 0; r < 4; ++r)
          m |= (acc[s][r] > 0.0f) ? (1u << (s * 4 + r)) : 0u;
      while (m) {
        int b = __ffs(m) - 1; m &= m - 1;
        int kl = (b >> 2) * 16 + lg * 4 + (b & 3);
        int slot = atomicAdd(&lcnt[kl], 1);
        if (slot < LSLOT) lhit[kl * LSLOT + slot] = (unsigned short)q;
      }
    }
  }
  __syncthreads();
  if (tid < 64) {
    int lc = lcnt[tid];
    int key = kbase + tid;
    unsigned add = (lc > LSLOT) ? (unsigned)(CAP + 1000) : (unsigned)lc;
    lbase[tid] = (lc > 0) ? (int)atomicAdd(&cnt[key], add) : 0;
    lcnt[tid] = lc < LSLOT ? lc : LSLOT;
  }
  __syncthreads();
  for (int idx = tid; idx < 64 * LSLOT; idx += 256) {
    int kl = idx >> 5, sl = idx & (LSLOT - 1);
    if (sl < lcnt[kl]) {
      int pos = lbase[kl] + sl;
      if (pos < CAP)
        cbuf[(size_t)(kbase + kl) * CAP + pos] = lhit[kl * LSLOT + sl];
    }
  }
}

// ---------------------------------------------------------------------------
// Kernel H (recheck v6, r20-measured body, 48 VGPR): block-per-key, 4 lanes
// per candidate with bit-exact segment-handoff chain. Rank-count selection;
// chunked full-scan fallback. Writes outIdx ONLY (dist separate — r21's
// fusion cost 32 VGPR and 14 points of occupancy).
// ---------------------------------------------------------------------------
__global__ __launch_bounds__(256) void knn_recheck(
    const float* __restrict__ keys, const float* __restrict__ queries,
    const float* __restrict__ k2a, const float* __restrict__ q2a,
    const unsigned* __restrict__ cnt, const unsigned short* __restrict__ cbuf,
    int CAP, int Nq, float* __restrict__ outIdx) {
  __shared__ unsigned long long packs[RBUF];       // 8.3 KB
  __shared__ unsigned long long cur16[KSEL];
  __shared__ float4 klds[16];
  int tid = threadIdx.x;
  int key = blockIdx.x;
  float myk2 = k2a[key];

  if (tid < 16)
    klds[tid] = reinterpret_cast<const float4*>(keys + (size_t)key * DDIM)[tid];
  __syncthreads();

  unsigned n = cnt[key];
  unsigned lim = (unsigned)((CAP < RFAST) ? CAP : RFAST);
  if (n <= lim) {
    const unsigned short* mc = cbuf + (size_t)key * CAP;
    int sub = tid & 3;
    int lanebase = (tid & 63) & ~3;
    for (unsigned base = 0; base < n; base += 64) {
      unsigned e = base + (unsigned)(tid >> 2);
      unsigned ec = (e < n) ? e : (n - 1);
      int j = mc[ec];
      const float4* Q = reinterpret_cast<const float4*>(queries + (size_t)j * DDIM);
      float4 rr[4];
      rr[0] = Q[sub];
      rr[1] = Q[sub + 4];
      rr[2] = Q[sub + 8];
      rr[3] = Q[sub + 12];
      float q2j = q2a[j];
      float c = 0.f;
#pragma unroll
      for (int seg = 0; seg < 16; ++seg) {
        float4 kk = klds[seg];
        float4 qq = rr[seg >> 2];
        float t = c;
        t = fmaf(kk.x, qq.x, t);
        t = fmaf(kk.y, qq.y, t);
        t = fmaf(kk.z, qq.z, t);
        t = fmaf(kk.w, qq.w, t);
        c = __shfl(t, lanebase + (seg & 3), 64);
      }
      if (e < n && sub == 0) {
        float d2 = __fsub_rn(__fadd_rn(myk2, q2j), __fmul_rn(2.0f, c));
        packs[e] = packdj(d2, j);
      }
    }
    __syncthreads();
    int N = (int)n;
    for (int i = tid; i < N; i += 256) {
      unsigned long long mp = packs[i];
      int c = 0;
      for (int m = 0; m < N; ++m) c += packs[m] < mp;
      if (c < KSEL)
        outIdx[(size_t)key * KSEL + c] = (float)(int)(mp & 0xFFFFFFFFull);
    }
    return;
  }

  // ---- fallback: exact full scan (correctness net, expected never) ----
  float bd[KSEL]; int bi[KSEL];
#pragma unroll
  for (int p = 0; p < KSEL; ++p) { bd[p] = FLT_MAX; bi[p] = INT_MAX; }
  const float* krow = keys + (size_t)key * DDIM;
  for (int j = tid; j < Nq; j += 256) {
    float d2 = exact_d2(krow, queries + (size_t)j * DDIM, myk2, q2a[j]);
    if (d2 < bd[KSEL - 1] || (d2 == bd[KSEL - 1] && j < bi[KSEL - 1]))
      insert16(bd, bi, d2, j);
  }
  if (tid < KSEL) cur16[tid] = ~0ull;
  __syncthreads();
  for (int r = 0; r < 4; ++r) {
    if ((tid >> 6) == r) {
#pragma unroll
      for (int p = 0; p < KSEL; ++p)
        packs[KSEL + (tid & 63) * KSEL + p] = packdj(bd[p], bi[p]);
    }
    if (tid < KSEL) packs[tid] = cur16[tid];
    __syncthreads();
    const int N = KSEL + 64 * KSEL;   // 1040
    for (int i = tid; i < N; i += 256) {
      unsigned long long mp = packs[i];
      int c = 0;
      for (int m = 0; m < N; ++m) c += packs[m] < mp;
      if (c < KSEL) cur16[c] = mp;
    }
    __syncthreads();
  }
  if (tid < KSEL)
    outIdx[(size_t)key * KSEL + tid] =
        (float)(int)(cur16[tid] & 0xFFFFFFFFull);
}

// ---------------------------------------------------------------------------
// Kernel I: recompute distances sum((k-q)^2) in f64, emit f32 (r20 body,
// validated r3-r20).
// ---------------------------------------------------------------------------
__global__ __launch_bounds__(256) void knn_dist_d(
    const float* __restrict__ keys, const float* __restrict__ queries,
    const float* __restrict__ outIdx, int Nk, float* __restrict__ outDist) {
  int e = blockIdx.x * 256 + threadIdx.x;
  if (e >= Nk * KSEL) return;
  int key = e >> 4;
  int id = (int)outIdx[e];
  const float* kp = keys + (size_t)key * DDIM;
  const float* qp = queries + (size_t)id * DDIM;
  double s = 0.0;
#pragma unroll
  for (int t = 0; t < DDIM; ++t) {
    double d = (double)kp[t] - (double)qp[t];
    s = fma(d, d, s);
  }
  outDist[e] = (float)s;
}

// ---------------------------------------------------------------------------
extern "C" void kernel_launch(void* const* d_in, const int* in_sizes, int n_in,
                              void* d_out, int out_size, void* d_ws, size_t ws_size,
                              hipStream_t stream) {
  const float* keys    = (const float*)d_in[0];
  const float* queries = (const float*)d_in[1];
  int Nk = in_sizes[0] / DDIM;   // 8192
  int Nq = in_sizes[1] / DDIM;   // 32768
  float* out = (float*)d_out;

  char* wp = (char*)d_ws;
  float*    k2  = (float*)wp;  wp += (size_t)Nk * 4;
  float*    q2  = (float*)wp;  wp += (size_t)Nq * 4;
  float*    sk  = (float*)wp;  wp += (size_t)Nk * 4;
  float*    sq  = (float*)wp;  wp += (size_t)Nq * 4;
  unsigned* cnt = (unsigned*)wp; wp += (size_t)Nk * 4;
  unsigned* cmin = (unsigned*)wp; wp += (size_t)Nk * NCHUNK * 4;   // 2 MB
  unsigned short* kbf = (unsigned short*)wp; wp += (size_t)Nk * DDIM * 2;
  unsigned short* qbf = (unsigned short*)wp; wp += (size_t)Nq * DDIM * 2;
  unsigned short* KE8 = (unsigned short*)wp; wp += (size_t)Nk * 8 * 2;
  unsigned short* QE8 = (unsigned short*)wp; wp += (size_t)Nq * 8 * 2;
  size_t fixedBytes = (size_t)(wp - (char*)d_ws);
  unsigned short* cbuf = (unsigned short*)wp;
  long long rem = (long long)ws_size - (long long)fixedBytes;
  int CAP = (int)(rem / (2 * (long long)Nk));
  if (CAP > 2048) CAP = 2048;
  if (CAP < 16) CAP = 16;

  knn_norms_np<<<(Nk + Nq + 255) / 256, 256, 0, stream>>>(
      keys, queries, Nk, Nq, k2, q2, sk, sq, kbf, qbf, QE8, cnt);
  knn_chunkmin<<<128 * (WINDOW / 256), 256, 0, stream>>>(
      kbf, qbf, k2, sk, q2, sq, cmin);
  knn_thresh3<<<(Nk + 255) / 256, 256, 0, stream>>>(cmin, k2, sk, Nk, KE8);
  knn_filter<<<128 * (Nq / 1024), 256, 0, stream>>>(
      kbf, qbf, KE8, QE8, cnt, cbuf, CAP);
  knn_recheck<<<Nk, 256, 0, stream>>>(
      keys, queries, k2, q2, cnt, cbuf, CAP, Nq, out);
  knn_dist_d<<<(Nk * KSEL + 255) / 256, 256, 0, stream>>>(
      keys, queries, out, Nk, out + (size_t)Nk * KSEL);
}

// Round 23
// 218.728 us; speedup vs baseline: 1.3557x; 1.0669x over previous
//
#include <hip/hip_runtime.h>
#include <hip/hip_bf16.h>
#include <cfloat>
#include <climits>

#define DDIM 64
#define KSEL 16
#define WINDOW 4096          // T-estimation window
#define NCHUNK 64            // chunks of 64 queries (one per wave)
#define C1 0.009f            // >= 2^-7 + 15% headroom: covers 2*bf16 dot error
                             // via Cauchy-Schwarz (r23: tightened from 0.017)
#define C2 0.05f             // covers f32 accumulation + threshold rounding
#define RFAST 1024           // fast-path candidate limit (block recheck)
#define RBUF 1040            // LDS pack slots: fast path <=1024; fallback 16+1024
#define LSLOT 32             // per-(key,block) LDS hit slots (main filter)

typedef __attribute__((ext_vector_type(8))) short short8;
typedef __attribute__((ext_vector_type(4))) float f32x4;

// ---------------------------------------------------------------------------
// numpy pairwise-sum emulation for n=64 contiguous f32 (validated r3-r22).
// ---------------------------------------------------------------------------
__device__ __forceinline__ float np_sum64(const float* p) {
  float lane[16];
#pragma unroll
  for (int j = 0; j < 16; ++j)
    lane[j] = __fadd_rn(__fadd_rn(p[j], p[16 + j]),
                        __fadd_rn(p[32 + j], p[48 + j]));
  float u[8];
#pragma unroll
  for (int j = 0; j < 8; ++j) u[j] = __fadd_rn(lane[j], lane[j + 8]);
  float w[4];
#pragma unroll
  for (int j = 0; j < 4; ++j) w[j] = __fadd_rn(u[j], u[j + 4]);
  return __fadd_rn(__fadd_rn(w[0], w[2]), __fadd_rn(w[1], w[3]));
}

__device__ __forceinline__ void insert16(float* bd, int* bi, float cd, int ci) {
#pragma unroll
  for (int p = 0; p < KSEL; ++p) {
    bool sm = (cd < bd[p]) || (cd == bd[p] && ci < bi[p]);
    float td = bd[p]; int ti = bi[p];
    bd[p] = sm ? cd : td; bi[p] = sm ? ci : ti;
    cd = sm ? td : cd;   ci = sm ? ti : ci;
  }
}

// Monotone map: lexicographic (d,j) ascending == u64 ascending (j distinct).
__device__ __forceinline__ unsigned long long packdj(float d, int j) {
  unsigned db = __float_as_uint(d);
  db = (db & 0x80000000u) ? ~db : (db | 0x80000000u);
  return ((unsigned long long)db << 32) | (unsigned)j;
}

__device__ __forceinline__ unsigned mapmono(float d) {
  unsigned db = __float_as_uint(d);
  return (db & 0x80000000u) ? ~db : (db | 0x80000000u);
}

__device__ __forceinline__ float unmapmono(unsigned m) {
  return (m & 0x80000000u) ? __uint_as_float(m & 0x7fffffffu)
                           : __uint_as_float(~m);
}

// np-exact d2: sequential fmaf chain (BLAS per-element order), validated r3.
__device__ __forceinline__ float exact_d2(const float* __restrict__ k,
                                          const float* __restrict__ q,
                                          float k2, float q2) {
  float c = 0.f;
#pragma unroll
  for (int t = 0; t < DDIM; ++t) c = fmaf(k[t], q[t], c);
  return __fsub_rn(__fadd_rn(k2, q2), __fmul_rn(2.0f, c));
}

__device__ __forceinline__ unsigned bf2pack(float a, float b) {
  __hip_bfloat16 ha = __float2bfloat16(a), hb = __float2bfloat16(b);
  unsigned short ua = *reinterpret_cast<unsigned short*>(&ha);
  unsigned short ub = *reinterpret_cast<unsigned short*>(&hb);
  return (unsigned)ua | ((unsigned)ub << 16);
}

// Directed bf16 rounding (toward -inf / +inf); exact negation is ^0x8000.
__device__ __forceinline__ unsigned short bf_down(float x) {
  unsigned u = __float_as_uint(x);
  unsigned short hs = (unsigned short)(u >> 16);
  if ((u & 0xFFFFu) && x < 0.0f) hs += 1;
  return hs;
}
__device__ __forceinline__ unsigned short bf_up(float x) {
  unsigned u = __float_as_uint(x);
  unsigned short hs = (unsigned short)(u >> 16);
  if ((u & 0xFFFFu) && x > 0.0f) hs += 1;
  return hs;
}
__device__ __forceinline__ float bf_val(unsigned short h) {
  return __uint_as_float(((unsigned)h) << 16);
}

// ---------------------------------------------------------------------------
// Kernel A: np-exact row norms + bf16 conversion + sqrt norms + query-side
// threshold-ext fragment QE; also zeroes cnt (i < Nk). Validated r18-r22.
// ---------------------------------------------------------------------------
__global__ __launch_bounds__(256) void knn_norms_np(
    const float* __restrict__ keys, const float* __restrict__ queries,
    int Nk, int Nq, float* __restrict__ k2, float* __restrict__ q2,
    float* __restrict__ sk, float* __restrict__ sq,
    unsigned short* __restrict__ kbf, unsigned short* __restrict__ qbf,
    unsigned short* __restrict__ QE8, unsigned* __restrict__ cnt) {
  int i = blockIdx.x * 256 + threadIdx.x;
  if (i >= Nk + Nq) return;
  if (i < Nk) cnt[i] = 0u;
  bool isK = i < Nk;
  int r = isK ? i : i - Nk;
  const float4* row4 = reinterpret_cast<const float4*>(
      (isK ? keys : queries) + (size_t)r * DDIM);
  float p[DDIM]; unsigned hw[DDIM / 2];
#pragma unroll
  for (int t = 0; t < 16; ++t) {
    float4 v = row4[t];
    p[4 * t + 0] = __fmul_rn(v.x, v.x);
    p[4 * t + 1] = __fmul_rn(v.y, v.y);
    p[4 * t + 2] = __fmul_rn(v.z, v.z);
    p[4 * t + 3] = __fmul_rn(v.w, v.w);
    hw[2 * t + 0] = bf2pack(v.x, v.y);
    hw[2 * t + 1] = bf2pack(v.z, v.w);
  }
  float s = np_sum64(p);
  uint4* dst = reinterpret_cast<uint4*>((isK ? kbf : qbf) + (size_t)r * DDIM);
#pragma unroll
  for (int t = 0; t < 8; ++t)
    dst[t] = make_uint4(hw[4 * t], hw[4 * t + 1], hw[4 * t + 2], hw[4 * t + 3]);
  if (isK) { k2[r] = s; sk[r] = sqrtf(s); }
  else {
    q2[r] = s;
    float sv = sqrtf(s);
    sq[r] = sv;
    float h = 0.5f * s;
    unsigned short hhi = bf_down(h);            // h > 0: trunc, <= h
    float rem = h - bf_val(hhi);                // >= 0
    unsigned short hlo = (rem > 0.f) ? bf_down(rem) : (unsigned short)0;
    unsigned short e[8] = {0x3F80, bf_up(sv), hhi, hlo, 0, 0, 0, 0};
    uint4* qe = reinterpret_cast<uint4*>(QE8 + (size_t)r * 8);
    *qe = make_uint4((unsigned)e[0] | ((unsigned)e[1] << 16),
                     (unsigned)e[2] | ((unsigned)e[3] << 16), 0u, 0u);
  }
}

// ---------------------------------------------------------------------------
// Kernel C (chunkmin): MFMA upper-bound minima over the window, 64 chunks of
// 64 queries (one per wave). Single writer per (key,chunk) slot -> plain
// store, no init. Validated r20-r22 math.
// ---------------------------------------------------------------------------
__global__ __launch_bounds__(256) void knn_chunkmin(
    const unsigned short* __restrict__ kbf, const unsigned short* __restrict__ qbf,
    const float* __restrict__ k2a, const float* __restrict__ ska,
    const float* __restrict__ q2a, const float* __restrict__ sqa,
    unsigned* __restrict__ cmin) {
  int tid = threadIdx.x, lane = tid & 63, w = tid >> 6;
  int kb = blockIdx.x & 127;
  int qt = blockIdx.x >> 7;              // 0..15
  int kbase = kb * 64;
  int qbase = qt * 256 + w * 64;
  int chunk = qbase >> 6;                // 0..63 (one per wave)
  int l16 = lane & 15, lg = lane >> 4;

  short8 a0[4], a1[4];
#pragma unroll
  for (int s = 0; s < 4; ++s) {
    const short8* krow = reinterpret_cast<const short8*>(
        kbf + (size_t)(kbase + s * 16 + l16) * DDIM);
    a0[s] = krow[lg]; a1[s] = krow[lg + 4];
  }
  float KA[16], KB[16];
#pragma unroll
  for (int s = 0; s < 4; ++s)
#pragma unroll
    for (int r = 0; r < 4; ++r) {
      int kk = kbase + s * 16 + lg * 4 + r;
      KA[s * 4 + r] = k2a[kk] + C2;
      KB[s * 4 + r] = C1 * ska[kk];
    }
  float mreg[16];
#pragma unroll
  for (int i = 0; i < 16; ++i) mreg[i] = FLT_MAX;

#pragma unroll
  for (int qs = 0; qs < 4; ++qs) {
    int q = qbase + qs * 16 + l16;
    const short8* qrow = reinterpret_cast<const short8*>(qbf + (size_t)q * DDIM);
    short8 b0 = qrow[lg], b1 = qrow[lg + 4];
    float q2l = q2a[q], sql = sqa[q];
    f32x4 acc[4];
#pragma unroll
    for (int s = 0; s < 4; ++s) {
      f32x4 z = {0.f, 0.f, 0.f, 0.f};
      z = __builtin_amdgcn_mfma_f32_16x16x32_bf16(a0[s], b0, z, 0, 0, 0);
      z = __builtin_amdgcn_mfma_f32_16x16x32_bf16(a1[s], b1, z, 0, 0, 0);
      acc[s] = z;
    }
#pragma unroll
    for (int s = 0; s < 4; ++s)
#pragma unroll
      for (int r = 0; r < 4; ++r) {
        int i = s * 4 + r;
        float u = fmaf(KB[i], sql, KA[i] + q2l) - 2.0f * acc[s][r];
        mreg[i] = fminf(mreg[i], u);
      }
  }
#pragma unroll
  for (int m = 1; m < 16; m <<= 1)
#pragma unroll
    for (int i = 0; i < 16; ++i)
      mreg[i] = fminf(mreg[i], __shfl_xor(mreg[i], m));
  if (l16 == 0) {
#pragma unroll
    for (int i = 0; i < 16; ++i) {
      int kk = kbase + (i >> 2) * 16 + lg * 4 + (i & 3);
      cmin[(size_t)kk * NCHUNK + chunk] = mapmono(mreg[i]);
    }
  }
}

// ---------------------------------------------------------------------------
// Kernel F (thresh3): thread per key. T = 16th-smallest of the 64 chunk
// minima (16 distinct pairs <= T => exact 16th <= T). Emits KE fragment
// (directed rounding -> filter superset). Validated r20-r22.
// ---------------------------------------------------------------------------
__global__ __launch_bounds__(256) void knn_thresh3(
    const unsigned* __restrict__ cmin,
    const float* __restrict__ k2a, const float* __restrict__ ska,
    int Nk, unsigned short* __restrict__ KE8) {
  int key = blockIdx.x * 256 + threadIdx.x;
  if (key >= Nk) return;
  unsigned b[KSEL];
#pragma unroll
  for (int p = 0; p < KSEL; ++p) b[p] = 0xFFFFFFFFu;
  const unsigned* row = cmin + (size_t)key * NCHUNK;
  for (int c = 0; c < NCHUNK; ++c) {
    unsigned v = row[c];
    if (v < b[KSEL - 1]) {
      unsigned cv = v;
#pragma unroll
      for (int p = 0; p < KSEL; ++p) {
        bool sm = cv < b[p];
        unsigned t = b[p];
        b[p] = sm ? cv : t;
        cv = sm ? t : cv;
      }
    }
  }
  float T = unmapmono(b[KSEL - 1]);
  float psA = 0.5f * (k2a[key] - T - C2);
  float psB = -0.5f * C1 * ska[key];
  unsigned short e0 = (unsigned short)(bf_down(psA) ^ 0x8000);
  unsigned short e1 = (unsigned short)(bf_down(psB) ^ 0x8000);
  uint4* ke = reinterpret_cast<uint4*>(KE8 + (size_t)key * 8);
  *ke = make_uint4((unsigned)e0 | ((unsigned)e1 << 16),
                   0xBF80u | (0xBF80u << 16), 0u, 0u);
}

// ---------------------------------------------------------------------------
// Kernel G (MFMA filter v6, r18/r20/r22-measured-best body): threshold
// folded into a third K=32 MFMA via KE/QE ext fragments; sign-test epilogue.
// Byte-identical to r22.
// ---------------------------------------------------------------------------
__global__ __launch_bounds__(256) void knn_filter(
    const unsigned short* __restrict__ kbf, const unsigned short* __restrict__ qbf,
    const unsigned short* __restrict__ KE8, const unsigned short* __restrict__ QE8,
    unsigned* __restrict__ cnt, unsigned short* __restrict__ cbuf, int CAP) {
  __shared__ int lcnt[64];
  __shared__ int lbase[64];
  __shared__ unsigned short lhit[64 * LSLOT];
  int tid = threadIdx.x;
  int lane = tid & 63, w = tid >> 6;
  int kb = blockIdx.x & 127;
  int qt = blockIdx.x >> 7;
  int kbase = kb * 64;
  int qwave = qt * 1024 + w * 256;
  int l16 = lane & 15, lg = lane >> 4;
  const short8 z8 = {0, 0, 0, 0, 0, 0, 0, 0};

  if (tid < 64) lcnt[tid] = 0;
  __syncthreads();

  short8 a0[4], a1[4], a2[4];
#pragma unroll
  for (int s = 0; s < 4; ++s) {
    const short8* krow = reinterpret_cast<const short8*>(
        kbf + (size_t)(kbase + s * 16 + l16) * DDIM);
    a0[s] = krow[lg]; a1[s] = krow[lg + 4];
    a2[s] = (lg == 0)
        ? *reinterpret_cast<const short8*>(KE8 + (size_t)(kbase + s * 16 + l16) * 8)
        : z8;
  }

  for (int qo = 0; qo < 4; ++qo) {
    int qbase = qwave + qo * 64;
#pragma unroll
    for (int qs = 0; qs < 4; ++qs) {
      int q = qbase + qs * 16 + l16;
      const short8* qrow = reinterpret_cast<const short8*>(qbf + (size_t)q * DDIM);
      short8 b0 = qrow[lg], b1 = qrow[lg + 4];
      short8 b2 = (lg == 0)
          ? *reinterpret_cast<const short8*>(QE8 + (size_t)q * 8)
          : z8;

      f32x4 acc[4];
#pragma unroll
      for (int s = 0; s < 4; ++s) {
        f32x4 z = {0.f, 0.f, 0.f, 0.f};
        z = __builtin_amdgcn_mfma_f32_16x16x32_bf16(a0[s], b0, z, 0, 0, 0);
        z = __builtin_amdgcn_mfma_f32_16x16x32_bf16(a1[s], b1, z, 0, 0, 0);
        z = __builtin_amdgcn_mfma_f32_16x16x32_bf16(a2[s], b2, z, 0, 0, 0);
        acc[s] = z;
      }
      unsigned m = 0;
#pragma unroll
      for (int s = 0; s < 4; ++s)
#pragma unroll
        for (int r = 0; r < 4; ++r)
          m |= (acc[s][r] > 0.0f) ? (1u << (s * 4 + r)) : 0u;
      while (m) {
        int b = __ffs(m) - 1; m &= m - 1;
        int kl = (b >> 2) * 16 + lg * 4 + (b & 3);
        int slot = atomicAdd(&lcnt[kl], 1);
        if (slot < LSLOT) lhit[kl * LSLOT + slot] = (unsigned short)q;
      }
    }
  }
  __syncthreads();
  if (tid < 64) {
    int lc = lcnt[tid];
    int key = kbase + tid;
    unsigned add = (lc > LSLOT) ? (unsigned)(CAP + 1000) : (unsigned)lc;
    lbase[tid] = (lc > 0) ? (int)atomicAdd(&cnt[key], add) : 0;
    lcnt[tid] = lc < LSLOT ? lc : LSLOT;
  }
  __syncthreads();
  for (int idx = tid; idx < 64 * LSLOT; idx += 256) {
    int kl = idx >> 5, sl = idx & (LSLOT - 1);
    if (sl < lcnt[kl]) {
      int pos = lbase[kl] + sl;
      if (pos < CAP)
        cbuf[(size_t)(kbase + kl) * CAP + pos] = lhit[kl * LSLOT + sl];
    }
  }
}

// ---------------------------------------------------------------------------
// Kernel H (recheck v6, r20/r22-measured body, 48 VGPR): block-per-key, 4
// lanes per candidate with bit-exact segment-handoff chain. Rank-count
// selection; chunked full-scan fallback. Writes outIdx only.
// ---------------------------------------------------------------------------
__global__ __launch_bounds__(256) void knn_recheck(
    const float* __restrict__ keys, const float* __restrict__ queries,
    const float* __restrict__ k2a, const float* __restrict__ q2a,
    const unsigned* __restrict__ cnt, const unsigned short* __restrict__ cbuf,
    int CAP, int Nq, float* __restrict__ outIdx) {
  __shared__ unsigned long long packs[RBUF];       // 8.3 KB
  __shared__ unsigned long long cur16[KSEL];
  __shared__ float4 klds[16];
  int tid = threadIdx.x;
  int key = blockIdx.x;
  float myk2 = k2a[key];

  if (tid < 16)
    klds[tid] = reinterpret_cast<const float4*>(keys + (size_t)key * DDIM)[tid];
  __syncthreads();

  unsigned n = cnt[key];
  unsigned lim = (unsigned)((CAP < RFAST) ? CAP : RFAST);
  if (n <= lim) {
    const unsigned short* mc = cbuf + (size_t)key * CAP;
    int sub = tid & 3;
    int lanebase = (tid & 63) & ~3;
    for (unsigned base = 0; base < n; base += 64) {
      unsigned e = base + (unsigned)(tid >> 2);
      unsigned ec = (e < n) ? e : (n - 1);
      int j = mc[ec];
      const float4* Q = reinterpret_cast<const float4*>(queries + (size_t)j * DDIM);
      float4 rr[4];
      rr[0] = Q[sub];
      rr[1] = Q[sub + 4];
      rr[2] = Q[sub + 8];
      rr[3] = Q[sub + 12];
      float q2j = q2a[j];
      float c = 0.f;
#pragma unroll
      for (int seg = 0; seg < 16; ++seg) {
        float4 kk = klds[seg];
        float4 qq = rr[seg >> 2];
        float t = c;
        t = fmaf(kk.x, qq.x, t);
        t = fmaf(kk.y, qq.y, t);
        t = fmaf(kk.z, qq.z, t);
        t = fmaf(kk.w, qq.w, t);
        c = __shfl(t, lanebase + (seg & 3), 64);
      }
      if (e < n && sub == 0) {
        float d2 = __fsub_rn(__fadd_rn(myk2, q2j), __fmul_rn(2.0f, c));
        packs[e] = packdj(d2, j);
      }
    }
    __syncthreads();
    int N = (int)n;
    for (int i = tid; i < N; i += 256) {
      unsigned long long mp = packs[i];
      int c = 0;
      for (int m = 0; m < N; ++m) c += packs[m] < mp;
      if (c < KSEL)
        outIdx[(size_t)key * KSEL + c] = (float)(int)(mp & 0xFFFFFFFFull);
    }
    return;
  }

  // ---- fallback: exact full scan (correctness net, expected never) ----
  float bd[KSEL]; int bi[KSEL];
#pragma unroll
  for (int p = 0; p < KSEL; ++p) { bd[p] = FLT_MAX; bi[p] = INT_MAX; }
  const float* krow = keys + (size_t)key * DDIM;
  for (int j = tid; j < Nq; j += 256) {
    float d2 = exact_d2(krow, queries + (size_t)j * DDIM, myk2, q2a[j]);
    if (d2 < bd[KSEL - 1] || (d2 == bd[KSEL - 1] && j < bi[KSEL - 1]))
      insert16(bd, bi, d2, j);
  }
  if (tid < KSEL) cur16[tid] = ~0ull;
  __syncthreads();
  for (int r = 0; r < 4; ++r) {
    if ((tid >> 6) == r) {
#pragma unroll
      for (int p = 0; p < KSEL; ++p)
        packs[KSEL + (tid & 63) * KSEL + p] = packdj(bd[p], bi[p]);
    }
    if (tid < KSEL) packs[tid] = cur16[tid];
    __syncthreads();
    const int N = KSEL + 64 * KSEL;   // 1040
    for (int i = tid; i < N; i += 256) {
      unsigned long long mp = packs[i];
      int c = 0;
      for (int m = 0; m < N; ++m) c += packs[m] < mp;
      if (c < KSEL) cur16[c] = mp;
    }
    __syncthreads();
  }
  if (tid < KSEL)
    outIdx[(size_t)key * KSEL + tid] =
        (float)(int)(cur16[tid] & 0xFFFFFFFFull);
}

// ---------------------------------------------------------------------------
// Kernel I: recompute distances sum((k-q)^2) in f64, emit f32 (validated).
// ---------------------------------------------------------------------------
__global__ __launch_bounds__(256) void knn_dist_d(
    const float* __restrict__ keys, const float* __restrict__ queries,
    const float* __restrict__ outIdx, int Nk, float* __restrict__ outDist) {
  int e = blockIdx.x * 256 + threadIdx.x;
  if (e >= Nk * KSEL) return;
  int key = e >> 4;
  int id = (int)outIdx[e];
  const float* kp = keys + (size_t)key * DDIM;
  const float* qp = queries + (size_t)id * DDIM;
  double s = 0.0;
#pragma unroll
  for (int t = 0; t < DDIM; ++t) {
    double d = (double)kp[t] - (double)qp[t];
    s = fma(d, d, s);
  }
  outDist[e] = (float)s;
}

// ---------------------------------------------------------------------------
extern "C" void kernel_launch(void* const* d_in, const int* in_sizes, int n_in,
                              void* d_out, int out_size, void* d_ws, size_t ws_size,
                              hipStream_t stream) {
  const float* keys    = (const float*)d_in[0];
  const float* queries = (const float*)d_in[1];
  int Nk = in_sizes[0] / DDIM;   // 8192
  int Nq = in_sizes[1] / DDIM;   // 32768
  float* out = (float*)d_out;

  char* wp = (char*)d_ws;
  float*    k2  = (float*)wp;  wp += (size_t)Nk * 4;
  float*    q2  = (float*)wp;  wp += (size_t)Nq * 4;
  float*    sk  = (float*)wp;  wp += (size_t)Nk * 4;
  float*    sq  = (float*)wp;  wp += (size_t)Nq * 4;
  unsigned* cnt = (unsigned*)wp; wp += (size_t)Nk * 4;
  unsigned* cmin = (unsigned*)wp; wp += (size_t)Nk * NCHUNK * 4;   // 2 MB
  unsigned short* kbf = (unsigned short*)wp; wp += (size_t)Nk * DDIM * 2;
  unsigned short* qbf = (unsigned short*)wp; wp += (size_t)Nq * DDIM * 2;
  unsigned short* KE8 = (unsigned short*)wp; wp += (size_t)Nk * 8 * 2;
  unsigned short* QE8 = (unsigned short*)wp; wp += (size_t)Nq * 8 * 2;
  size_t fixedBytes = (size_t)(wp - (char*)d_ws);
  unsigned short* cbuf = (unsigned short*)wp;
  long long rem = (long long)ws_size - (long long)fixedBytes;
  int CAP = (int)(rem / (2 * (long long)Nk));
  if (CAP > 2048) CAP = 2048;
  if (CAP < 16) CAP = 16;

  knn_norms_np<<<(Nk + Nq + 255) / 256, 256, 0, stream>>>(
      keys, queries, Nk, Nq, k2, q2, sk, sq, kbf, qbf, QE8, cnt);
  knn_chunkmin<<<128 * (WINDOW / 256), 256, 0, stream>>>(
      kbf, qbf, k2, sk, q2, sq, cmin);
  knn_thresh3<<<(Nk + 255) / 256, 256, 0, stream>>>(cmin, k2, sk, Nk, KE8);
  knn_filter<<<128 * (Nq / 1024), 256, 0, stream>>>(
      kbf, qbf, KE8, QE8, cnt, cbuf, CAP);
  knn_recheck<<<Nk, 256, 0, stream>>>(
      keys, queries, k2, q2, cnt, cbuf, CAP, Nq, out);
  knn_dist_d<<<(Nk * KSEL + 255) / 256, 256, 0, stream>>>(
      keys, queries, out, Nk, out + (size_t)Nk * KSEL);
}

// Round 24
// 215.616 us; speedup vs baseline: 1.3752x; 1.0144x over previous
//
#include <hip/hip_runtime.h>
#include <hip/hip_bf16.h>
#include <cfloat>
#include <climits>

#define DDIM 64
#define KSEL 16
#define WINDOW 4096          // T-estimation window
#define NCHUNK 64            // chunks of 64 queries (one per wave)
#define C1 0.009f            // >= 2^-7 + headroom: covers 2*bf16 dot error
#define C2 0.05f             // covers f32 accumulation + threshold rounding
#define RFAST 1024           // fast-path candidate limit (block recheck)
#define RBUF 1040            // LDS pack slots: fast path <=1024; fallback 16+1024
#define LSLOT 32             // per-(key,block) LDS hit slots (main filter)

typedef __attribute__((ext_vector_type(8))) short short8;
typedef __attribute__((ext_vector_type(4))) float f32x4;
typedef __attribute__((ext_vector_type(16))) float f32x16;

// ---------------------------------------------------------------------------
// numpy pairwise-sum emulation for n=64 contiguous f32 (validated r3-r23).
// ---------------------------------------------------------------------------
__device__ __forceinline__ float np_sum64(const float* p) {
  float lane[16];
#pragma unroll
  for (int j = 0; j < 16; ++j)
    lane[j] = __fadd_rn(__fadd_rn(p[j], p[16 + j]),
                        __fadd_rn(p[32 + j], p[48 + j]));
  float u[8];
#pragma unroll
  for (int j = 0; j < 8; ++j) u[j] = __fadd_rn(lane[j], lane[j + 8]);
  float w[4];
#pragma unroll
  for (int j = 0; j < 4; ++j) w[j] = __fadd_rn(u[j], u[j + 4]);
  return __fadd_rn(__fadd_rn(w[0], w[2]), __fadd_rn(w[1], w[3]));
}

__device__ __forceinline__ void insert16(float* bd, int* bi, float cd, int ci) {
#pragma unroll
  for (int p = 0; p < KSEL; ++p) {
    bool sm = (cd < bd[p]) || (cd == bd[p] && ci < bi[p]);
    float td = bd[p]; int ti = bi[p];
    bd[p] = sm ? cd : td; bi[p] = sm ? ci : ti;
    cd = sm ? td : cd;   ci = sm ? ti : ci;
  }
}

// Monotone map: lexicographic (d,j) ascending == u64 ascending (j distinct).
__device__ __forceinline__ unsigned long long packdj(float d, int j) {
  unsigned db = __float_as_uint(d);
  db = (db & 0x80000000u) ? ~db : (db | 0x80000000u);
  return ((unsigned long long)db << 32) | (unsigned)j;
}

__device__ __forceinline__ unsigned mapmono(float d) {
  unsigned db = __float_as_uint(d);
  return (db & 0x80000000u) ? ~db : (db | 0x80000000u);
}

__device__ __forceinline__ float unmapmono(unsigned m) {
  return (m & 0x80000000u) ? __uint_as_float(m & 0x7fffffffu)
                           : __uint_as_float(~m);
}

// np-exact d2: sequential fmaf chain (BLAS per-element order), validated r3.
__device__ __forceinline__ float exact_d2(const float* __restrict__ k,
                                          const float* __restrict__ q,
                                          float k2, float q2) {
  float c = 0.f;
#pragma unroll
  for (int t = 0; t < DDIM; ++t) c = fmaf(k[t], q[t], c);
  return __fsub_rn(__fadd_rn(k2, q2), __fmul_rn(2.0f, c));
}

__device__ __forceinline__ unsigned bf2pack(float a, float b) {
  __hip_bfloat16 ha = __float2bfloat16(a), hb = __float2bfloat16(b);
  unsigned short ua = *reinterpret_cast<unsigned short*>(&ha);
  unsigned short ub = *reinterpret_cast<unsigned short*>(&hb);
  return (unsigned)ua | ((unsigned)ub << 16);
}

// Directed bf16 rounding (toward -inf / +inf); exact negation is ^0x8000.
__device__ __forceinline__ unsigned short bf_down(float x) {
  unsigned u = __float_as_uint(x);
  unsigned short hs = (unsigned short)(u >> 16);
  if ((u & 0xFFFFu) && x < 0.0f) hs += 1;
  return hs;
}
__device__ __forceinline__ unsigned short bf_up(float x) {
  unsigned u = __float_as_uint(x);
  unsigned short hs = (unsigned short)(u >> 16);
  if ((u & 0xFFFFu) && x > 0.0f) hs += 1;
  return hs;
}
__device__ __forceinline__ float bf_val(unsigned short h) {
  return __uint_as_float(((unsigned)h) << 16);
}

// ---------------------------------------------------------------------------
// Kernel A: np-exact row norms + bf16 conversion + sqrt norms + query-side
// threshold-ext fragment QE; also zeroes cnt (i < Nk). Validated r18-r23.
// ---------------------------------------------------------------------------
__global__ __launch_bounds__(256) void knn_norms_np(
    const float* __restrict__ keys, const float* __restrict__ queries,
    int Nk, int Nq, float* __restrict__ k2, float* __restrict__ q2,
    float* __restrict__ sk, float* __restrict__ sq,
    unsigned short* __restrict__ kbf, unsigned short* __restrict__ qbf,
    unsigned short* __restrict__ QE8, unsigned* __restrict__ cnt) {
  int i = blockIdx.x * 256 + threadIdx.x;
  if (i >= Nk + Nq) return;
  if (i < Nk) cnt[i] = 0u;
  bool isK = i < Nk;
  int r = isK ? i : i - Nk;
  const float4* row4 = reinterpret_cast<const float4*>(
      (isK ? keys : queries) + (size_t)r * DDIM);
  float p[DDIM]; unsigned hw[DDIM / 2];
#pragma unroll
  for (int t = 0; t < 16; ++t) {
    float4 v = row4[t];
    p[4 * t + 0] = __fmul_rn(v.x, v.x);
    p[4 * t + 1] = __fmul_rn(v.y, v.y);
    p[4 * t + 2] = __fmul_rn(v.z, v.z);
    p[4 * t + 3] = __fmul_rn(v.w, v.w);
    hw[2 * t + 0] = bf2pack(v.x, v.y);
    hw[2 * t + 1] = bf2pack(v.z, v.w);
  }
  float s = np_sum64(p);
  uint4* dst = reinterpret_cast<uint4*>((isK ? kbf : qbf) + (size_t)r * DDIM);
#pragma unroll
  for (int t = 0; t < 8; ++t)
    dst[t] = make_uint4(hw[4 * t], hw[4 * t + 1], hw[4 * t + 2], hw[4 * t + 3]);
  if (isK) { k2[r] = s; sk[r] = sqrtf(s); }
  else {
    q2[r] = s;
    float sv = sqrtf(s);
    sq[r] = sv;
    float h = 0.5f * s;
    unsigned short hhi = bf_down(h);            // h > 0: trunc, <= h
    float rem = h - bf_val(hhi);                // >= 0
    unsigned short hlo = (rem > 0.f) ? bf_down(rem) : (unsigned short)0;
    unsigned short e[8] = {0x3F80, bf_up(sv), hhi, hlo, 0, 0, 0, 0};
    uint4* qe = reinterpret_cast<uint4*>(QE8 + (size_t)r * 8);
    *qe = make_uint4((unsigned)e[0] | ((unsigned)e[1] << 16),
                     (unsigned)e[2] | ((unsigned)e[3] << 16), 0u, 0u);
  }
}

// ---------------------------------------------------------------------------
// Kernel C (chunkmin): MFMA upper-bound minima over the window, 64 chunks of
// 64 queries (one per wave). Single writer per (key,chunk) slot -> plain
// store, no init. Validated r20-r23 math.
// ---------------------------------------------------------------------------
__global__ __launch_bounds__(256) void knn_chunkmin(
    const unsigned short* __restrict__ kbf, const unsigned short* __restrict__ qbf,
    const float* __restrict__ k2a, const float* __restrict__ ska,
    const float* __restrict__ q2a, const float* __restrict__ sqa,
    unsigned* __restrict__ cmin) {
  int tid = threadIdx.x, lane = tid & 63, w = tid >> 6;
  int kb = blockIdx.x & 127;
  int qt = blockIdx.x >> 7;              // 0..15
  int kbase = kb * 64;
  int qbase = qt * 256 + w * 64;
  int chunk = qbase >> 6;                // 0..63 (one per wave)
  int l16 = lane & 15, lg = lane >> 4;

  short8 a0[4], a1[4];
#pragma unroll
  for (int s = 0; s < 4; ++s) {
    const short8* krow = reinterpret_cast<const short8*>(
        kbf + (size_t)(kbase + s * 16 + l16) * DDIM);
    a0[s] = krow[lg]; a1[s] = krow[lg + 4];
  }
  float KA[16], KB[16];
#pragma unroll
  for (int s = 0; s < 4; ++s)
#pragma unroll
    for (int r = 0; r < 4; ++r) {
      int kk = kbase + s * 16 + lg * 4 + r;
      KA[s * 4 + r] = k2a[kk] + C2;
      KB[s * 4 + r] = C1 * ska[kk];
    }
  float mreg[16];
#pragma unroll
  for (int i = 0; i < 16; ++i) mreg[i] = FLT_MAX;

#pragma unroll
  for (int qs = 0; qs < 4; ++qs) {
    int q = qbase + qs * 16 + l16;
    const short8* qrow = reinterpret_cast<const short8*>(qbf + (size_t)q * DDIM);
    short8 b0 = qrow[lg], b1 = qrow[lg + 4];
    float q2l = q2a[q], sql = sqa[q];
    f32x4 acc[4];
#pragma unroll
    for (int s = 0; s < 4; ++s) {
      f32x4 z = {0.f, 0.f, 0.f, 0.f};
      z = __builtin_amdgcn_mfma_f32_16x16x32_bf16(a0[s], b0, z, 0, 0, 0);
      z = __builtin_amdgcn_mfma_f32_16x16x32_bf16(a1[s], b1, z, 0, 0, 0);
      acc[s] = z;
    }
#pragma unroll
    for (int s = 0; s < 4; ++s)
#pragma unroll
      for (int r = 0; r < 4; ++r) {
        int i = s * 4 + r;
        float u = fmaf(KB[i], sql, KA[i] + q2l) - 2.0f * acc[s][r];
        mreg[i] = fminf(mreg[i], u);
      }
  }
#pragma unroll
  for (int m = 1; m < 16; m <<= 1)
#pragma unroll
    for (int i = 0; i < 16; ++i)
      mreg[i] = fminf(mreg[i], __shfl_xor(mreg[i], m));
  if (l16 == 0) {
#pragma unroll
    for (int i = 0; i < 16; ++i) {
      int kk = kbase + (i >> 2) * 16 + lg * 4 + (i & 3);
      cmin[(size_t)kk * NCHUNK + chunk] = mapmono(mreg[i]);
    }
  }
}

// ---------------------------------------------------------------------------
// Kernel F (thresh3): thread per key. T = 16th-smallest of the 64 chunk
// minima. Emits KE fragment (directed rounding -> filter superset).
// Validated r20-r23.
// ---------------------------------------------------------------------------
__global__ __launch_bounds__(256) void knn_thresh3(
    const unsigned* __restrict__ cmin,
    const float* __restrict__ k2a, const float* __restrict__ ska,
    int Nk, unsigned short* __restrict__ KE8) {
  int key = blockIdx.x * 256 + threadIdx.x;
  if (key >= Nk) return;
  unsigned b[KSEL];
#pragma unroll
  for (int p = 0; p < KSEL; ++p) b[p] = 0xFFFFFFFFu;
  const unsigned* row = cmin + (size_t)key * NCHUNK;
  for (int c = 0; c < NCHUNK; ++c) {
    unsigned v = row[c];
    if (v < b[KSEL - 1]) {
      unsigned cv = v;
#pragma unroll
      for (int p = 0; p < KSEL; ++p) {
        bool sm = cv < b[p];
        unsigned t = b[p];
        b[p] = sm ? cv : t;
        cv = sm ? t : cv;
      }
    }
  }
  float T = unmapmono(b[KSEL - 1]);
  float psA = 0.5f * (k2a[key] - T - C2);
  float psB = -0.5f * C1 * ska[key];
  unsigned short e0 = (unsigned short)(bf_down(psA) ^ 0x8000);
  unsigned short e1 = (unsigned short)(bf_down(psB) ^ 0x8000);
  uint4* ke = reinterpret_cast<uint4*>(KE8 + (size_t)key * 8);
  *ke = make_uint4((unsigned)e0 | ((unsigned)e1 << 16),
                   0xBF80u | (0xBF80u << 16), 0u, 0u);
}

// ---------------------------------------------------------------------------
// Kernel G (MFMA filter v8): 32x32x16 MFMA tiles. Wave = 64 keys (2 tiles of
// 32) x 32 queries per step, 8 steps (256 q/wave). Per step: 4 K-chunk MFMAs
// + 1 threshold MFMA per tile = 10 MFMA / 2048 pairs (was 24). Threshold
// KE/QE fragments land in k=0..7 of lanes<32 (zeros elsewhere) — same
// buffers as r18-r23. C/D layout (HW-verified): col=lane&31,
// row=(reg&3)+8*(reg>>2)+4*(lane>>5). Sign-test epilogue; LDS hit
// aggregation + flush byte-identical to r23.
// ---------------------------------------------------------------------------
__global__ __launch_bounds__(256) void knn_filter(
    const unsigned short* __restrict__ kbf, const unsigned short* __restrict__ qbf,
    const unsigned short* __restrict__ KE8, const unsigned short* __restrict__ QE8,
    unsigned* __restrict__ cnt, unsigned short* __restrict__ cbuf, int CAP) {
  __shared__ int lcnt[64];
  __shared__ int lbase[64];
  __shared__ unsigned short lhit[64 * LSLOT];
  int tid = threadIdx.x;
  int lane = tid & 63, w = tid >> 6;
  int kb = blockIdx.x & 127;
  int qt = blockIdx.x >> 7;
  int kbase = kb * 64;
  int qwave = qt * 1024 + w * 256;
  int l32 = lane & 31, hi = lane >> 5;
  const short8 z8 = {0, 0, 0, 0, 0, 0, 0, 0};

  if (tid < 64) lcnt[tid] = 0;
  __syncthreads();

  // A fragments: 2 key tiles x 4 K-chunks (row = l32, k = c*16 + hi*8 ..+8)
  short8 a[2][4], aext[2];
#pragma unroll
  for (int t = 0; t < 2; ++t) {
    const unsigned short* krow = kbf + (size_t)(kbase + t * 32 + l32) * DDIM;
#pragma unroll
    for (int c = 0; c < 4; ++c)
      a[t][c] = *reinterpret_cast<const short8*>(krow + c * 16 + hi * 8);
    aext[t] = (hi == 0)
        ? *reinterpret_cast<const short8*>(KE8 + (size_t)(kbase + t * 32 + l32) * 8)
        : z8;
  }

  for (int st = 0; st < 8; ++st) {
    int q = qwave + st * 32 + l32;
    const unsigned short* qrow = qbf + (size_t)q * DDIM;
    short8 b[4];
#pragma unroll
    for (int c = 0; c < 4; ++c)
      b[c] = *reinterpret_cast<const short8*>(qrow + c * 16 + hi * 8);
    short8 bext = (hi == 0)
        ? *reinterpret_cast<const short8*>(QE8 + (size_t)q * 8) : z8;

#pragma unroll
    for (int t = 0; t < 2; ++t) {
      f32x16 z = {0.f, 0.f, 0.f, 0.f, 0.f, 0.f, 0.f, 0.f,
                  0.f, 0.f, 0.f, 0.f, 0.f, 0.f, 0.f, 0.f};
      z = __builtin_amdgcn_mfma_f32_32x32x16_bf16(a[t][0], b[0], z, 0, 0, 0);
      z = __builtin_amdgcn_mfma_f32_32x32x16_bf16(a[t][1], b[1], z, 0, 0, 0);
      z = __builtin_amdgcn_mfma_f32_32x32x16_bf16(a[t][2], b[2], z, 0, 0, 0);
      z = __builtin_amdgcn_mfma_f32_32x32x16_bf16(a[t][3], b[3], z, 0, 0, 0);
      z = __builtin_amdgcn_mfma_f32_32x32x16_bf16(aext[t], bext, z, 0, 0, 0);
      unsigned m = 0;
#pragma unroll
      for (int r = 0; r < 16; ++r)
        m |= (z[r] > 0.0f) ? (1u << r) : 0u;
      while (m) {
        int r = __ffs(m) - 1; m &= m - 1;
        int kl = t * 32 + (r & 3) + 8 * (r >> 2) + 4 * hi;
        int slot = atomicAdd(&lcnt[kl], 1);
        if (slot < LSLOT) lhit[kl * LSLOT + slot] = (unsigned short)q;
      }
    }
  }
  __syncthreads();
  if (tid < 64) {
    int lc = lcnt[tid];
    int key = kbase + tid;
    unsigned add = (lc > LSLOT) ? (unsigned)(CAP + 1000) : (unsigned)lc;
    lbase[tid] = (lc > 0) ? (int)atomicAdd(&cnt[key], add) : 0;
    lcnt[tid] = lc < LSLOT ? lc : LSLOT;
  }
  __syncthreads();
  for (int idx = tid; idx < 64 * LSLOT; idx += 256) {
    int kl = idx >> 5, sl = idx & (LSLOT - 1);
    if (sl < lcnt[kl]) {
      int pos = lbase[kl] + sl;
      if (pos < CAP)
        cbuf[(size_t)(kbase + kl) * CAP + pos] = lhit[kl * LSLOT + sl];
    }
  }
}

// ---------------------------------------------------------------------------
// Kernel H (recheck v6, r20/r22/r23-measured body, 48 VGPR): block-per-key,
// 4 lanes per candidate with bit-exact segment-handoff chain. Rank-count
// selection; chunked full-scan fallback. Writes outIdx only.
// ---------------------------------------------------------------------------
__global__ __launch_bounds__(256) void knn_recheck(
    const float* __restrict__ keys, const float* __restrict__ queries,
    const float* __restrict__ k2a, const float* __restrict__ q2a,
    const unsigned* __restrict__ cnt, const unsigned short* __restrict__ cbuf,
    int CAP, int Nq, float* __restrict__ outIdx) {
  __shared__ unsigned long long packs[RBUF];       // 8.3 KB
  __shared__ unsigned long long cur16[KSEL];
  __shared__ float4 klds[16];
  int tid = threadIdx.x;
  int key = blockIdx.x;
  float myk2 = k2a[key];

  if (tid < 16)
    klds[tid] = reinterpret_cast<const float4*>(keys + (size_t)key * DDIM)[tid];
  __syncthreads();

  unsigned n = cnt[key];
  unsigned lim = (unsigned)((CAP < RFAST) ? CAP : RFAST);
  if (n <= lim) {
    const unsigned short* mc = cbuf + (size_t)key * CAP;
    int sub = tid & 3;
    int lanebase = (tid & 63) & ~3;
    for (unsigned base = 0; base < n; base += 64) {
      unsigned e = base + (unsigned)(tid >> 2);
      unsigned ec = (e < n) ? e : (n - 1);
      int j = mc[ec];
      const float4* Q = reinterpret_cast<const float4*>(queries + (size_t)j * DDIM);
      float4 rr[4];
      rr[0] = Q[sub];
      rr[1] = Q[sub + 4];
      rr[2] = Q[sub + 8];
      rr[3] = Q[sub + 12];
      float q2j = q2a[j];
      float c = 0.f;
#pragma unroll
      for (int seg = 0; seg < 16; ++seg) {
        float4 kk = klds[seg];
        float4 qq = rr[seg >> 2];
        float t = c;
        t = fmaf(kk.x, qq.x, t);
        t = fmaf(kk.y, qq.y, t);
        t = fmaf(kk.z, qq.z, t);
        t = fmaf(kk.w, qq.w, t);
        c = __shfl(t, lanebase + (seg & 3), 64);
      }
      if (e < n && sub == 0) {
        float d2 = __fsub_rn(__fadd_rn(myk2, q2j), __fmul_rn(2.0f, c));
        packs[e] = packdj(d2, j);
      }
    }
    __syncthreads();
    int N = (int)n;
    for (int i = tid; i < N; i += 256) {
      unsigned long long mp = packs[i];
      int c = 0;
      for (int m = 0; m < N; ++m) c += packs[m] < mp;
      if (c < KSEL)
        outIdx[(size_t)key * KSEL + c] = (float)(int)(mp & 0xFFFFFFFFull);
    }
    return;
  }

  // ---- fallback: exact full scan (correctness net, expected never) ----
  float bd[KSEL]; int bi[KSEL];
#pragma unroll
  for (int p = 0; p < KSEL; ++p) { bd[p] = FLT_MAX; bi[p] = INT_MAX; }
  const float* krow = keys + (size_t)key * DDIM;
  for (int j = tid; j < Nq; j += 256) {
    float d2 = exact_d2(krow, queries + (size_t)j * DDIM, myk2, q2a[j]);
    if (d2 < bd[KSEL - 1] || (d2 == bd[KSEL - 1] && j < bi[KSEL - 1]))
      insert16(bd, bi, d2, j);
  }
  if (tid < KSEL) cur16[tid] = ~0ull;
  __syncthreads();
  for (int r = 0; r < 4; ++r) {
    if ((tid >> 6) == r) {
#pragma unroll
      for (int p = 0; p < KSEL; ++p)
        packs[KSEL + (tid & 63) * KSEL + p] = packdj(bd[p], bi[p]);
    }
    if (tid < KSEL) packs[tid] = cur16[tid];
    __syncthreads();
    const int N = KSEL + 64 * KSEL;   // 1040
    for (int i = tid; i < N; i += 256) {
      unsigned long long mp = packs[i];
      int c = 0;
      for (int m = 0; m < N; ++m) c += packs[m] < mp;
      if (c < KSEL) cur16[c] = mp;
    }
    __syncthreads();
  }
  if (tid < KSEL)
    outIdx[(size_t)key * KSEL + tid] =
        (float)(int)(cur16[tid] & 0xFFFFFFFFull);
}

// ---------------------------------------------------------------------------
// Kernel I: recompute distances sum((k-q)^2) in f64, emit f32 (validated).
// ---------------------------------------------------------------------------
__global__ __launch_bounds__(256) void knn_dist_d(
    const float* __restrict__ keys, const float* __restrict__ queries,
    const float* __restrict__ outIdx, int Nk, float* __restrict__ outDist) {
  int e = blockIdx.x * 256 + threadIdx.x;
  if (e >= Nk * KSEL) return;
  int key = e >> 4;
  int id = (int)outIdx[e];
  const float* kp = keys + (size_t)key * DDIM;
  const float* qp = queries + (size_t)id * DDIM;
  double s = 0.0;
#pragma unroll
  for (int t = 0; t < DDIM; ++t) {
    double d = (double)kp[t] - (double)qp[t];
    s = fma(d, d, s);
  }
  outDist[e] = (float)s;
}

// ---------------------------------------------------------------------------
extern "C" void kernel_launch(void* const* d_in, const int* in_sizes, int n_in,
                              void* d_out, int out_size, void* d_ws, size_t ws_size,
                              hipStream_t stream) {
  const float* keys    = (const float*)d_in[0];
  const float* queries = (const float*)d_in[1];
  int Nk = in_sizes[0] / DDIM;   // 8192
  int Nq = in_sizes[1] / DDIM;   // 32768
  float* out = (float*)d_out;

  char* wp = (char*)d_ws;
  float*    k2  = (float*)wp;  wp += (size_t)Nk * 4;
  float*    q2  = (float*)wp;  wp += (size_t)Nq * 4;
  float*    sk  = (float*)wp;  wp += (size_t)Nk * 4;
  float*    sq  = (float*)wp;  wp += (size_t)Nq * 4;
  unsigned* cnt = (unsigned*)wp; wp += (size_t)Nk * 4;
  unsigned* cmin = (unsigned*)wp; wp += (size_t)Nk * NCHUNK * 4;   // 2 MB
  unsigned short* kbf = (unsigned short*)wp; wp += (size_t)Nk * DDIM * 2;
  unsigned short* qbf = (unsigned short*)wp; wp += (size_t)Nq * DDIM * 2;
  unsigned short* KE8 = (unsigned short*)wp; wp += (size_t)Nk * 8 * 2;
  unsigned short* QE8 = (unsigned short*)wp; wp += (size_t)Nq * 8 * 2;
  size_t fixedBytes = (size_t)(wp - (char*)d_ws);
  unsigned short* cbuf = (unsigned short*)wp;
  long long rem = (long long)ws_size - (long long)fixedBytes;
  int CAP = (int)(rem / (2 * (long long)Nk));
  if (CAP > 2048) CAP = 2048;
  if (CAP < 16) CAP = 16;

  knn_norms_np<<<(Nk + Nq + 255) / 256, 256, 0, stream>>>(
      keys, queries, Nk, Nq, k2, q2, sk, sq, kbf, qbf, QE8, cnt);
  knn_chunkmin<<<128 * (WINDOW / 256), 256, 0, stream>>>(
      kbf, qbf, k2, sk, q2, sq, cmin);
  knn_thresh3<<<(Nk + 255) / 256, 256, 0, stream>>>(cmin, k2, sk, Nk, KE8);
  knn_filter<<<128 * (Nq / 1024), 256, 0, stream>>>(
      kbf, qbf, KE8, QE8, cnt, cbuf, CAP);
  knn_recheck<<<Nk, 256, 0, stream>>>(
      keys, queries, k2, q2, cnt, cbuf, CAP, Nq, out);
  knn_dist_d<<<(Nk * KSEL + 255) / 256, 256, 0, stream>>>(
      keys, queries, out, Nk, out + (size_t)Nk * KSEL);
}

// Round 25
// 214.909 us; speedup vs baseline: 1.3797x; 1.0033x over previous
//
#include <hip/hip_runtime.h>
#include <hip/hip_bf16.h>
#include <cfloat>
#include <climits>

#define DDIM 64
#define KSEL 16
#define WINDOW 4096          // T-estimation window
#define NCHUNK 64            // chunks of 64 queries (one per wave)
#define C1 0.009f            // >= 2^-7 + headroom: covers 2*bf16 dot error
#define C2 0.05f             // covers f32 accumulation + threshold rounding
#define RFAST 1024           // fast-path candidate limit (block recheck)
#define RBUF 1040            // LDS pack slots: fast path <=1024; fallback 16+1024
#define LSLOT 32             // per-(key,block) LDS hit slots (main filter)

typedef __attribute__((ext_vector_type(8))) short short8;
typedef __attribute__((ext_vector_type(4))) float f32x4;
typedef __attribute__((ext_vector_type(16))) float f32x16;

// ---------------------------------------------------------------------------
// numpy pairwise-sum emulation for n=64 contiguous f32 (validated r3-r24).
// ---------------------------------------------------------------------------
__device__ __forceinline__ float np_sum64(const float* p) {
  float lane[16];
#pragma unroll
  for (int j = 0; j < 16; ++j)
    lane[j] = __fadd_rn(__fadd_rn(p[j], p[16 + j]),
                        __fadd_rn(p[32 + j], p[48 + j]));
  float u[8];
#pragma unroll
  for (int j = 0; j < 8; ++j) u[j] = __fadd_rn(lane[j], lane[j + 8]);
  float w[4];
#pragma unroll
  for (int j = 0; j < 4; ++j) w[j] = __fadd_rn(u[j], u[j + 4]);
  return __fadd_rn(__fadd_rn(w[0], w[2]), __fadd_rn(w[1], w[3]));
}

__device__ __forceinline__ void insert16(float* bd, int* bi, float cd, int ci) {
#pragma unroll
  for (int p = 0; p < KSEL; ++p) {
    bool sm = (cd < bd[p]) || (cd == bd[p] && ci < bi[p]);
    float td = bd[p]; int ti = bi[p];
    bd[p] = sm ? cd : td; bi[p] = sm ? ci : ti;
    cd = sm ? td : cd;   ci = sm ? ti : ci;
  }
}

// Monotone map: lexicographic (d,j) ascending == u64 ascending (j distinct).
__device__ __forceinline__ unsigned long long packdj(float d, int j) {
  unsigned db = __float_as_uint(d);
  db = (db & 0x80000000u) ? ~db : (db | 0x80000000u);
  return ((unsigned long long)db << 32) | (unsigned)j;
}

__device__ __forceinline__ unsigned mapmono(float d) {
  unsigned db = __float_as_uint(d);
  return (db & 0x80000000u) ? ~db : (db | 0x80000000u);
}

__device__ __forceinline__ float unmapmono(unsigned m) {
  return (m & 0x80000000u) ? __uint_as_float(m & 0x7fffffffu)
                           : __uint_as_float(~m);
}

// np-exact d2: sequential fmaf chain (BLAS per-element order), validated r3.
__device__ __forceinline__ float exact_d2(const float* __restrict__ k,
                                          const float* __restrict__ q,
                                          float k2, float q2) {
  float c = 0.f;
#pragma unroll
  for (int t = 0; t < DDIM; ++t) c = fmaf(k[t], q[t], c);
  return __fsub_rn(__fadd_rn(k2, q2), __fmul_rn(2.0f, c));
}

__device__ __forceinline__ unsigned bf2pack(float a, float b) {
  __hip_bfloat16 ha = __float2bfloat16(a), hb = __float2bfloat16(b);
  unsigned short ua = *reinterpret_cast<unsigned short*>(&ha);
  unsigned short ub = *reinterpret_cast<unsigned short*>(&hb);
  return (unsigned)ua | ((unsigned)ub << 16);
}

// Directed bf16 rounding (toward -inf / +inf); exact negation is ^0x8000.
__device__ __forceinline__ unsigned short bf_down(float x) {
  unsigned u = __float_as_uint(x);
  unsigned short hs = (unsigned short)(u >> 16);
  if ((u & 0xFFFFu) && x < 0.0f) hs += 1;
  return hs;
}
__device__ __forceinline__ unsigned short bf_up(float x) {
  unsigned u = __float_as_uint(x);
  unsigned short hs = (unsigned short)(u >> 16);
  if ((u & 0xFFFFu) && x > 0.0f) hs += 1;
  return hs;
}
__device__ __forceinline__ float bf_val(unsigned short h) {
  return __uint_as_float(((unsigned)h) << 16);
}

// ---------------------------------------------------------------------------
// Kernel A: np-exact row norms + bf16 conversion + sqrt norms + query-side
// threshold-ext fragment QE; also zeroes cnt (i < Nk). Validated r18-r24.
// ---------------------------------------------------------------------------
__global__ __launch_bounds__(256) void knn_norms_np(
    const float* __restrict__ keys, const float* __restrict__ queries,
    int Nk, int Nq, float* __restrict__ k2, float* __restrict__ q2,
    float* __restrict__ sk, float* __restrict__ sq,
    unsigned short* __restrict__ kbf, unsigned short* __restrict__ qbf,
    unsigned short* __restrict__ QE8, unsigned* __restrict__ cnt) {
  int i = blockIdx.x * 256 + threadIdx.x;
  if (i >= Nk + Nq) return;
  if (i < Nk) cnt[i] = 0u;
  bool isK = i < Nk;
  int r = isK ? i : i - Nk;
  const float4* row4 = reinterpret_cast<const float4*>(
      (isK ? keys : queries) + (size_t)r * DDIM);
  float p[DDIM]; unsigned hw[DDIM / 2];
#pragma unroll
  for (int t = 0; t < 16; ++t) {
    float4 v = row4[t];
    p[4 * t + 0] = __fmul_rn(v.x, v.x);
    p[4 * t + 1] = __fmul_rn(v.y, v.y);
    p[4 * t + 2] = __fmul_rn(v.z, v.z);
    p[4 * t + 3] = __fmul_rn(v.w, v.w);
    hw[2 * t + 0] = bf2pack(v.x, v.y);
    hw[2 * t + 1] = bf2pack(v.z, v.w);
  }
  float s = np_sum64(p);
  uint4* dst = reinterpret_cast<uint4*>((isK ? kbf : qbf) + (size_t)r * DDIM);
#pragma unroll
  for (int t = 0; t < 8; ++t)
    dst[t] = make_uint4(hw[4 * t], hw[4 * t + 1], hw[4 * t + 2], hw[4 * t + 3]);
  if (isK) { k2[r] = s; sk[r] = sqrtf(s); }
  else {
    q2[r] = s;
    float sv = sqrtf(s);
    sq[r] = sv;
    float h = 0.5f * s;
    unsigned short hhi = bf_down(h);            // h > 0: trunc, <= h
    float rem = h - bf_val(hhi);                // >= 0
    unsigned short hlo = (rem > 0.f) ? bf_down(rem) : (unsigned short)0;
    unsigned short e[8] = {0x3F80, bf_up(sv), hhi, hlo, 0, 0, 0, 0};
    uint4* qe = reinterpret_cast<uint4*>(QE8 + (size_t)r * 8);
    *qe = make_uint4((unsigned)e[0] | ((unsigned)e[1] << 16),
                     (unsigned)e[2] | ((unsigned)e[3] << 16), 0u, 0u);
  }
}

// ---------------------------------------------------------------------------
// Kernel C (chunkmin): MFMA upper-bound minima over the window, 64 chunks of
// 64 queries (one per wave). Single writer per (key,chunk) slot -> plain
// store, no init. Validated r20-r24 math.
// ---------------------------------------------------------------------------
__global__ __launch_bounds__(256) void knn_chunkmin(
    const unsigned short* __restrict__ kbf, const unsigned short* __restrict__ qbf,
    const float* __restrict__ k2a, const float* __restrict__ ska,
    const float* __restrict__ q2a, const float* __restrict__ sqa,
    unsigned* __restrict__ cmin) {
  int tid = threadIdx.x, lane = tid & 63, w = tid >> 6;
  int kb = blockIdx.x & 127;
  int qt = blockIdx.x >> 7;              // 0..15
  int kbase = kb * 64;
  int qbase = qt * 256 + w * 64;
  int chunk = qbase >> 6;                // 0..63 (one per wave)
  int l16 = lane & 15, lg = lane >> 4;

  short8 a0[4], a1[4];
#pragma unroll
  for (int s = 0; s < 4; ++s) {
    const short8* krow = reinterpret_cast<const short8*>(
        kbf + (size_t)(kbase + s * 16 + l16) * DDIM);
    a0[s] = krow[lg]; a1[s] = krow[lg + 4];
  }
  float KA[16], KB[16];
#pragma unroll
  for (int s = 0; s < 4; ++s)
#pragma unroll
    for (int r = 0; r < 4; ++r) {
      int kk = kbase + s * 16 + lg * 4 + r;
      KA[s * 4 + r] = k2a[kk] + C2;
      KB[s * 4 + r] = C1 * ska[kk];
    }
  float mreg[16];
#pragma unroll
  for (int i = 0; i < 16; ++i) mreg[i] = FLT_MAX;

#pragma unroll
  for (int qs = 0; qs < 4; ++qs) {
    int q = qbase + qs * 16 + l16;
    const short8* qrow = reinterpret_cast<const short8*>(qbf + (size_t)q * DDIM);
    short8 b0 = qrow[lg], b1 = qrow[lg + 4];
    float q2l = q2a[q], sql = sqa[q];
    f32x4 acc[4];
#pragma unroll
    for (int s = 0; s < 4; ++s) {
      f32x4 z = {0.f, 0.f, 0.f, 0.f};
      z = __builtin_amdgcn_mfma_f32_16x16x32_bf16(a0[s], b0, z, 0, 0, 0);
      z = __builtin_amdgcn_mfma_f32_16x16x32_bf16(a1[s], b1, z, 0, 0, 0);
      acc[s] = z;
    }
#pragma unroll
    for (int s = 0; s < 4; ++s)
#pragma unroll
      for (int r = 0; r < 4; ++r) {
        int i = s * 4 + r;
        float u = fmaf(KB[i], sql, KA[i] + q2l) - 2.0f * acc[s][r];
        mreg[i] = fminf(mreg[i], u);
      }
  }
#pragma unroll
  for (int m = 1; m < 16; m <<= 1)
#pragma unroll
    for (int i = 0; i < 16; ++i)
      mreg[i] = fminf(mreg[i], __shfl_xor(mreg[i], m));
  if (l16 == 0) {
#pragma unroll
    for (int i = 0; i < 16; ++i) {
      int kk = kbase + (i >> 2) * 16 + lg * 4 + (i & 3);
      cmin[(size_t)kk * NCHUNK + chunk] = mapmono(mreg[i]);
    }
  }
}

// ---------------------------------------------------------------------------
// Kernel F (thresh3): thread per key. T = 16th-smallest of the 64 chunk
// minima. Emits KE fragment (directed rounding -> filter superset).
// Validated r20-r24.
// ---------------------------------------------------------------------------
__global__ __launch_bounds__(256) void knn_thresh3(
    const unsigned* __restrict__ cmin,
    const float* __restrict__ k2a, const float* __restrict__ ska,
    int Nk, unsigned short* __restrict__ KE8) {
  int key = blockIdx.x * 256 + threadIdx.x;
  if (key >= Nk) return;
  unsigned b[KSEL];
#pragma unroll
  for (int p = 0; p < KSEL; ++p) b[p] = 0xFFFFFFFFu;
  const unsigned* row = cmin + (size_t)key * NCHUNK;
  for (int c = 0; c < NCHUNK; ++c) {
    unsigned v = row[c];
    if (v < b[KSEL - 1]) {
      unsigned cv = v;
#pragma unroll
      for (int p = 0; p < KSEL; ++p) {
        bool sm = cv < b[p];
        unsigned t = b[p];
        b[p] = sm ? cv : t;
        cv = sm ? t : cv;
      }
    }
  }
  float T = unmapmono(b[KSEL - 1]);
  float psA = 0.5f * (k2a[key] - T - C2);
  float psB = -0.5f * C1 * ska[key];
  unsigned short e0 = (unsigned short)(bf_down(psA) ^ 0x8000);
  unsigned short e1 = (unsigned short)(bf_down(psB) ^ 0x8000);
  uint4* ke = reinterpret_cast<uint4*>(KE8 + (size_t)key * 8);
  *ke = make_uint4((unsigned)e0 | ((unsigned)e1 << 16),
                   0xBF80u | (0xBF80u << 16), 0u, 0u);
}

// ---------------------------------------------------------------------------
// Kernel G (MFMA filter v9): r24's 32x32x16 body with a SIGN-WORD epilogue:
// s |= sign(z[r]) << r  (lshr + lshl_or, 2 VALU/elem vs 3 for cmp+sel+or),
// m = ~s & 0xFFFF. Bit set <=> z[r] >= +0 — a SUPERSET of z[r] > 0 (only
// measure-zero acc==0 pairs added; recheck is exact so output unchanged).
// Everything else byte-identical to r24.
// ---------------------------------------------------------------------------
__global__ __launch_bounds__(256) void knn_filter(
    const unsigned short* __restrict__ kbf, const unsigned short* __restrict__ qbf,
    const unsigned short* __restrict__ KE8, const unsigned short* __restrict__ QE8,
    unsigned* __restrict__ cnt, unsigned short* __restrict__ cbuf, int CAP) {
  __shared__ int lcnt[64];
  __shared__ int lbase[64];
  __shared__ unsigned short lhit[64 * LSLOT];
  int tid = threadIdx.x;
  int lane = tid & 63, w = tid >> 6;
  int kb = blockIdx.x & 127;
  int qt = blockIdx.x >> 7;
  int kbase = kb * 64;
  int qwave = qt * 1024 + w * 256;
  int l32 = lane & 31, hi = lane >> 5;
  const short8 z8 = {0, 0, 0, 0, 0, 0, 0, 0};

  if (tid < 64) lcnt[tid] = 0;
  __syncthreads();

  // A fragments: 2 key tiles x 4 K-chunks (row = l32, k = c*16 + hi*8 ..+8)
  short8 a[2][4], aext[2];
#pragma unroll
  for (int t = 0; t < 2; ++t) {
    const unsigned short* krow = kbf + (size_t)(kbase + t * 32 + l32) * DDIM;
#pragma unroll
    for (int c = 0; c < 4; ++c)
      a[t][c] = *reinterpret_cast<const short8*>(krow + c * 16 + hi * 8);
    aext[t] = (hi == 0)
        ? *reinterpret_cast<const short8*>(KE8 + (size_t)(kbase + t * 32 + l32) * 8)
        : z8;
  }

  for (int st = 0; st < 8; ++st) {
    int q = qwave + st * 32 + l32;
    const unsigned short* qrow = qbf + (size_t)q * DDIM;
    short8 b[4];
#pragma unroll
    for (int c = 0; c < 4; ++c)
      b[c] = *reinterpret_cast<const short8*>(qrow + c * 16 + hi * 8);
    short8 bext = (hi == 0)
        ? *reinterpret_cast<const short8*>(QE8 + (size_t)q * 8) : z8;

#pragma unroll
    for (int t = 0; t < 2; ++t) {
      f32x16 z = {0.f, 0.f, 0.f, 0.f, 0.f, 0.f, 0.f, 0.f,
                  0.f, 0.f, 0.f, 0.f, 0.f, 0.f, 0.f, 0.f};
      z = __builtin_amdgcn_mfma_f32_32x32x16_bf16(a[t][0], b[0], z, 0, 0, 0);
      z = __builtin_amdgcn_mfma_f32_32x32x16_bf16(a[t][1], b[1], z, 0, 0, 0);
      z = __builtin_amdgcn_mfma_f32_32x32x16_bf16(a[t][2], b[2], z, 0, 0, 0);
      z = __builtin_amdgcn_mfma_f32_32x32x16_bf16(a[t][3], b[3], z, 0, 0, 0);
      z = __builtin_amdgcn_mfma_f32_32x32x16_bf16(aext[t], bext, z, 0, 0, 0);
      unsigned s = 0;
#pragma unroll
      for (int r = 0; r < 16; ++r)
        s |= (__float_as_uint(z[r]) >> 31) << r;
      unsigned m = (~s) & 0xFFFFu;
      while (m) {
        int r = __ffs(m) - 1; m &= m - 1;
        int kl = t * 32 + (r & 3) + 8 * (r >> 2) + 4 * hi;
        int slot = atomicAdd(&lcnt[kl], 1);
        if (slot < LSLOT) lhit[kl * LSLOT + slot] = (unsigned short)q;
      }
    }
  }
  __syncthreads();
  if (tid < 64) {
    int lc = lcnt[tid];
    int key = kbase + tid;
    unsigned add = (lc > LSLOT) ? (unsigned)(CAP + 1000) : (unsigned)lc;
    lbase[tid] = (lc > 0) ? (int)atomicAdd(&cnt[key], add) : 0;
    lcnt[tid] = lc < LSLOT ? lc : LSLOT;
  }
  __syncthreads();
  for (int idx = tid; idx < 64 * LSLOT; idx += 256) {
    int kl = idx >> 5, sl = idx & (LSLOT - 1);
    if (sl < lcnt[kl]) {
      int pos = lbase[kl] + sl;
      if (pos < CAP)
        cbuf[(size_t)(kbase + kl) * CAP + pos] = lhit[kl * LSLOT + sl];
    }
  }
}

// ---------------------------------------------------------------------------
// Kernel H (recheck v6, r20/r22-r24-measured body, 48 VGPR): block-per-key,
// 4 lanes per candidate with bit-exact segment-handoff chain. Rank-count
// selection; chunked full-scan fallback. Writes outIdx only.
// ---------------------------------------------------------------------------
__global__ __launch_bounds__(256) void knn_recheck(
    const float* __restrict__ keys, const float* __restrict__ queries,
    const float* __restrict__ k2a, const float* __restrict__ q2a,
    const unsigned* __restrict__ cnt, const unsigned short* __restrict__ cbuf,
    int CAP, int Nq, float* __restrict__ outIdx) {
  __shared__ unsigned long long packs[RBUF];       // 8.3 KB
  __shared__ unsigned long long cur16[KSEL];
  __shared__ float4 klds[16];
  int tid = threadIdx.x;
  int key = blockIdx.x;
  float myk2 = k2a[key];

  if (tid < 16)
    klds[tid] = reinterpret_cast<const float4*>(keys + (size_t)key * DDIM)[tid];
  __syncthreads();

  unsigned n = cnt[key];
  unsigned lim = (unsigned)((CAP < RFAST) ? CAP : RFAST);
  if (n <= lim) {
    const unsigned short* mc = cbuf + (size_t)key * CAP;
    int sub = tid & 3;
    int lanebase = (tid & 63) & ~3;
    for (unsigned base = 0; base < n; base += 64) {
      unsigned e = base + (unsigned)(tid >> 2);
      unsigned ec = (e < n) ? e : (n - 1);
      int j = mc[ec];
      const float4* Q = reinterpret_cast<const float4*>(queries + (size_t)j * DDIM);
      float4 rr[4];
      rr[0] = Q[sub];
      rr[1] = Q[sub + 4];
      rr[2] = Q[sub + 8];
      rr[3] = Q[sub + 12];
      float q2j = q2a[j];
      float c = 0.f;
#pragma unroll
      for (int seg = 0; seg < 16; ++seg) {
        float4 kk = klds[seg];
        float4 qq = rr[seg >> 2];
        float t = c;
        t = fmaf(kk.x, qq.x, t);
        t = fmaf(kk.y, qq.y, t);
        t = fmaf(kk.z, qq.z, t);
        t = fmaf(kk.w, qq.w, t);
        c = __shfl(t, lanebase + (seg & 3), 64);
      }
      if (e < n && sub == 0) {
        float d2 = __fsub_rn(__fadd_rn(myk2, q2j), __fmul_rn(2.0f, c));
        packs[e] = packdj(d2, j);
      }
    }
    __syncthreads();
    int N = (int)n;
    for (int i = tid; i < N; i += 256) {
      unsigned long long mp = packs[i];
      int c = 0;
      for (int m = 0; m < N; ++m) c += packs[m] < mp;
      if (c < KSEL)
        outIdx[(size_t)key * KSEL + c] = (float)(int)(mp & 0xFFFFFFFFull);
    }
    return;
  }

  // ---- fallback: exact full scan (correctness net, expected never) ----
  float bd[KSEL]; int bi[KSEL];
#pragma unroll
  for (int p = 0; p < KSEL; ++p) { bd[p] = FLT_MAX; bi[p] = INT_MAX; }
  const float* krow = keys + (size_t)key * DDIM;
  for (int j = tid; j < Nq; j += 256) {
    float d2 = exact_d2(krow, queries + (size_t)j * DDIM, myk2, q2a[j]);
    if (d2 < bd[KSEL - 1] || (d2 == bd[KSEL - 1] && j < bi[KSEL - 1]))
      insert16(bd, bi, d2, j);
  }
  if (tid < KSEL) cur16[tid] = ~0ull;
  __syncthreads();
  for (int r = 0; r < 4; ++r) {
    if ((tid >> 6) == r) {
#pragma unroll
      for (int p = 0; p < KSEL; ++p)
        packs[KSEL + (tid & 63) * KSEL + p] = packdj(bd[p], bi[p]);
    }
    if (tid < KSEL) packs[tid] = cur16[tid];
    __syncthreads();
    const int N = KSEL + 64 * KSEL;   // 1040
    for (int i = tid; i < N; i += 256) {
      unsigned long long mp = packs[i];
      int c = 0;
      for (int m = 0; m < N; ++m) c += packs[m] < mp;
      if (c < KSEL) cur16[c] = mp;
    }
    __syncthreads();
  }
  if (tid < KSEL)
    outIdx[(size_t)key * KSEL + tid] =
        (float)(int)(cur16[tid] & 0xFFFFFFFFull);
}

// ---------------------------------------------------------------------------
// Kernel I: recompute distances sum((k-q)^2) in f64, emit f32 (validated).
// ---------------------------------------------------------------------------
__global__ __launch_bounds__(256) void knn_dist_d(
    const float* __restrict__ keys, const float* __restrict__ queries,
    const float* __restrict__ outIdx, int Nk, float* __restrict__ outDist) {
  int e = blockIdx.x * 256 + threadIdx.x;
  if (e >= Nk * KSEL) return;
  int key = e >> 4;
  int id = (int)outIdx[e];
  const float* kp = keys + (size_t)key * DDIM;
  const float* qp = queries + (size_t)id * DDIM;
  double s = 0.0;
#pragma unroll
  for (int t = 0; t < DDIM; ++t) {
    double d = (double)kp[t] - (double)qp[t];
    s = fma(d, d, s);
  }
  outDist[e] = (float)s;
}

// ---------------------------------------------------------------------------
extern "C" void kernel_launch(void* const* d_in, const int* in_sizes, int n_in,
                              void* d_out, int out_size, void* d_ws, size_t ws_size,
                              hipStream_t stream) {
  const float* keys    = (const float*)d_in[0];
  const float* queries = (const float*)d_in[1];
  int Nk = in_sizes[0] / DDIM;   // 8192
  int Nq = in_sizes[1] / DDIM;   // 32768
  float* out = (float*)d_out;

  char* wp = (char*)d_ws;
  float*    k2  = (float*)wp;  wp += (size_t)Nk * 4;
  float*    q2  = (float*)wp;  wp += (size_t)Nq * 4;
  float*    sk  = (float*)wp;  wp += (size_t)Nk * 4;
  float*    sq  = (float*)wp;  wp += (size_t)Nq * 4;
  unsigned* cnt = (unsigned*)wp; wp += (size_t)Nk * 4;
  unsigned* cmin = (unsigned*)wp; wp += (size_t)Nk * NCHUNK * 4;   // 2 MB
  unsigned short* kbf = (unsigned short*)wp; wp += (size_t)Nk * DDIM * 2;
  unsigned short* qbf = (unsigned short*)wp; wp += (size_t)Nq * DDIM * 2;
  unsigned short* KE8 = (unsigned short*)wp; wp += (size_t)Nk * 8 * 2;
  unsigned short* QE8 = (unsigned short*)wp; wp += (size_t)Nq * 8 * 2;
  size_t fixedBytes = (size_t)(wp - (char*)d_ws);
  unsigned short* cbuf = (unsigned short*)wp;
  long long rem = (long long)ws_size - (long long)fixedBytes;
  int CAP = (int)(rem / (2 * (long long)Nk));
  if (CAP > 2048) CAP = 2048;
  if (CAP < 16) CAP = 16;

  knn_norms_np<<<(Nk + Nq + 255) / 256, 256, 0, stream>>>(
      keys, queries, Nk, Nq, k2, q2, sk, sq, kbf, qbf, QE8, cnt);
  knn_chunkmin<<<128 * (WINDOW / 256), 256, 0, stream>>>(
      kbf, qbf, k2, sk, q2, sq, cmin);
  knn_thresh3<<<(Nk + 255) / 256, 256, 0, stream>>>(cmin, k2, sk, Nk, KE8);
  knn_filter<<<128 * (Nq / 1024), 256, 0, stream>>>(
      kbf, qbf, KE8, QE8, cnt, cbuf, CAP);
  knn_recheck<<<Nk, 256, 0, stream>>>(
      keys, queries, k2, q2, cnt, cbuf, CAP, Nq, out);
  knn_dist_d<<<(Nk * KSEL + 255) / 256, 256, 0, stream>>>(
      keys, queries, out, Nk, out + (size_t)Nk * KSEL);
}